// Round 9
// baseline (279.322 us; speedup 1.0000x reference)
//
#include <hip/hip_runtime.h>
#include <hip/hip_bf16.h>

#define N_NODES 50000
#define N_EDGES 800000
#define IN_CH   128
#define HID     256
#define OUTC    51

#define QSZ 3200000  // bytes per fp8 quarter region (N_NODES*64)

typedef __attribute__((ext_vector_type(8))) short  bf16x8;
typedef __attribute__((ext_vector_type(4))) float  f32x4;
typedef __attribute__((ext_vector_type(2))) float  f32x2;
typedef __attribute__((ext_vector_type(4))) unsigned int u32x4;

__device__ __forceinline__ float bf2f(unsigned short u) {
    union { unsigned int i; float f; } v; v.i = ((unsigned int)u) << 16; return v.f;
}
__device__ __forceinline__ unsigned short f2bf(float f) {
    union { float f; unsigned int i; } v; v.f = f;
    unsigned int u = v.i;
    unsigned int r = (u + 0x7fffu + ((u >> 16) & 1u)) >> 16;  // RNE
    return (unsigned short)r;
}
__device__ __forceinline__ unsigned short ldbf(const void* p, long i, int isf) {
    return isf ? f2bf(((const float*)p)[i]) : ((const unsigned short*)p)[i];
}
__device__ __forceinline__ float ldf(const void* p, long i, int isf) {
    return isf ? ((const float*)p)[i] : bf2f(((const unsigned short*)p)[i]);
}
__device__ __forceinline__ void load_edge_nt(const int* __restrict__ ei, int e, int is64,
                                             int* src, int* dst) {
    if (is64) { *src = __builtin_nontemporal_load(ei + 2 * e);
                *dst = __builtin_nontemporal_load(ei + 2 * (N_EDGES + e)); }
    else      { *src = __builtin_nontemporal_load(ei + e);
                *dst = __builtin_nontemporal_load(ei + N_EDGES + e); }
}

// async global->LDS 16B: wave-uniform LDS base, per-lane global src, HW dest = base + lane*16
typedef const __attribute__((address_space(1))) unsigned int* gas_u32;
typedef __attribute__((address_space(3))) unsigned int* las_u32;
__device__ __forceinline__ void cp16(const void* g, void* l) {
    __builtin_amdgcn_global_load_lds((gas_u32)g, (las_u32)l, 16, 0, 0);
}

// ---- radix-CSR constants ----
#define EBLK 1024                                // edges per histogram/fill block
#define HB   ((N_EDGES + EBLK - 1) / EBLK)       // 782 blocks
#define NBKT ((N_NODES + 255) / 256)             // 196 buckets of 256 nodes

// ---- quartered agg2: 4 contiguous fp8 quarter regions, XCD-pinned via blockIdx%8 ----
#define NCHUNK ((N_NODES + 63) / 64)             // 782 chunks of 64 nodes
#define ABLKQ  (NCHUNK * 4)                      // 3128 blocks; bid%8 in {q, q+4}

// ---------------- init: dtype probe + int64 detect (device probe is MANDATORY:
// in_sizes may be element counts, and fp32 vs bf16 have identical counts) ----------------
__global__ __launch_bounds__(256) void init_kernel(const unsigned int* __restrict__ x0w,
                                                   int* __restrict__ flags,
                                                   const int* __restrict__ ei) {
    int tid = threadIdx.x;
    if (blockIdx.x == 0) {
        if (tid < 64) {
            unsigned int w = x0w[tid];
            unsigned int ex = (w >> 7) & 0xFFu;
            unsigned long long bm = __ballot(ex >= 0x60u && ex <= 0x90u);
            if (tid == 0) flags[0] = (__popcll(bm) >= 48) ? 0 : 1;
        }
        return;
    }
    __shared__ int any;
    if (tid == 0) any = 0;
    __syncthreads();
    int acc = 0;
    for (int s = 0; s < 8; s++) {
        int i = (tid * 8 + s) * (N_EDGES / 2048);
        acc |= ei[2 * i + 1];
    }
    if (acc != 0) any = 1;
    __syncthreads();
    if (tid == 0) flags[1] = any;
}

// ---------------- prep_all: x0 convert (fp32 only, 8 elem/thr) + weight prep + edge histogram ----------------
__global__ void prep_all_kernel(const void* __restrict__ x0, int cb,
                                const void* __restrict__ w1r, const void* __restrict__ w1x,
                                const void* __restrict__ w2r, const void* __restrict__ w2x,
                                const void* __restrict__ lw,
                                const void* __restrict__ b1h, const void* __restrict__ b2h,
                                const void* __restrict__ lbh, const int* __restrict__ flags,
                                unsigned short* __restrict__ x0bf,
                                unsigned short* __restrict__ Bt1, unsigned short* __restrict__ Bt2,
                                unsigned short* __restrict__ Bt3,
                                float* __restrict__ b1, float* __restrict__ b2, float* __restrict__ b3,
                                const int* __restrict__ ei, unsigned int* __restrict__ bc,
                                int pblocks) {
    __shared__ unsigned int cnt[NBKT];
    int isf = flags[0];
    if ((int)blockIdx.x < cb) {
        if (!isf) return;  // bf16 input: skip copy
        long t0 = ((long)blockIdx.x * 256 + threadIdx.x) * 8;   // cb*256*8 == N*IN_CH exactly
        const float* xf = (const float*)x0;
        f32x4 v0 = *(const f32x4*)(xf + t0);
        f32x4 v1 = *(const f32x4*)(xf + t0 + 4);
        u32x4 pk;
        pk[0] = (unsigned int)f2bf(v0[0]) | ((unsigned int)f2bf(v0[1]) << 16);
        pk[1] = (unsigned int)f2bf(v0[2]) | ((unsigned int)f2bf(v0[3]) << 16);
        pk[2] = (unsigned int)f2bf(v1[0]) | ((unsigned int)f2bf(v1[1]) << 16);
        pk[3] = (unsigned int)f2bf(v1[2]) | ((unsigned int)f2bf(v1[3]) << 16);
        *(u32x4*)(x0bf + t0) = pk;
        return;
    }
    int rb = blockIdx.x - cb;
    if (rb >= pblocks) {
        // ---- histogram block ----
        int b = rb - pblocks;
        int tid = threadIdx.x;
        if (tid < NBKT) cnt[tid] = 0;
        __syncthreads();
        int is64 = (flags[1] == 0);
        int e0 = b * EBLK;
#pragma unroll
        for (int u = 0; u < 4; u++) {
            int e = e0 + u * 256 + tid;
            if (e < N_EDGES) {
                int src, dst; load_edge_nt(ei, e, is64, &src, &dst);
                if ((unsigned)src < N_NODES && (unsigned)dst < N_NODES)
                    atomicAdd(&cnt[dst >> 8], 1u);
            }
        }
        __syncthreads();
        if (tid < NBKT) bc[tid * HB + b] = cnt[tid];  // [bucket][block]
        return;
    }
    int t = rb * 256 + threadIdx.x;
    if (t < 256 * 256) {
        int n = t >> 8, k = t & 255;
        Bt1[n * 256 + k] = (k < 128) ? ldbf(w1r, k * 256 + n, isf) : ldbf(w1x, (k - 128) * 256 + n, isf);
        return;
    }
    t -= 256 * 256;
    if (t < 256 * 512) {
        int n = t >> 9, k = t & 511;
        Bt2[n * 512 + k] = (k < 256) ? ldbf(w2r, k * 256 + n, isf) : ldbf(w2x, (k - 256) * 256 + n, isf);
        return;
    }
    t -= 256 * 512;
    if (t < 64 * 512) {
        int n = t >> 9, k = t & 511;
        Bt3[n * 512 + k] = (n < OUTC) ? ldbf(lw, k * OUTC + n, isf) : (unsigned short)0;
        return;
    }
    t -= 64 * 512;
    if (t < 256) { b1[t] = ldf(b1h, t, isf); return; }
    t -= 256;
    if (t < 256) { b2[t] = ldf(b2h, t, isf); return; }
    t -= 256;
    if (t < 64)  { b3[t] = (t < OUTC) ? ldf(lbh, t, isf) : 0.0f; return; }
}

// ---------------- radix CSR scan 1: per-bucket prefix over blocks ----------------
__global__ __launch_bounds__(1024) void s1_kernel(const unsigned int* __restrict__ bc,
                                                  unsigned int* __restrict__ pbase,
                                                  unsigned int* __restrict__ total) {
    __shared__ unsigned int sd[1024];
    int b = blockIdx.x, tid = threadIdx.x;
    unsigned int v = (tid < HB) ? bc[b * HB + tid] : 0u;
    sd[tid] = v;
    __syncthreads();
    for (int off = 1; off < 1024; off <<= 1) {
        unsigned int t = (tid >= off) ? sd[tid - off] : 0u;
        __syncthreads();
        sd[tid] += t;
        __syncthreads();
    }
    if (tid < HB) pbase[tid * NBKT + b] = sd[tid] - v;  // [block][bucket], exclusive
    if (tid == 1023) total[b] = sd[1023];
}

// ---------------- radix CSR fill 1: scatter (w|src,dst) records into bucket regions ----------------
__global__ __launch_bounds__(256) void f1_kernel(const int* __restrict__ ei, const void* __restrict__ ew,
                                                 const int* __restrict__ flags,
                                                 const unsigned int* __restrict__ pbase,
                                                 const unsigned int* __restrict__ btot,
                                                 uint2* __restrict__ rec) {
    __shared__ unsigned int cur[NBKT];
    __shared__ unsigned int sb[256];
    int tid = threadIdx.x;
    unsigned int v = (tid < NBKT) ? btot[tid] : 0u;
    sb[tid] = v;
    __syncthreads();
    for (int off = 1; off < 256; off <<= 1) {
        unsigned int t = (tid >= off) ? sb[tid - off] : 0u;
        __syncthreads();
        sb[tid] += t;
        __syncthreads();
    }
    if (tid < NBKT) cur[tid] = (sb[tid] - v) + pbase[blockIdx.x * NBKT + tid];
    __syncthreads();
    int is64 = (flags[1] == 0);
    int isf = flags[0];
    int e0 = blockIdx.x * EBLK;
#pragma unroll
    for (int u = 0; u < 4; u++) {
        int e = e0 + u * 256 + tid;
        if (e < N_EDGES) {
            int src, dst; load_edge_nt(ei, e, is64, &src, &dst);
            if ((unsigned)src < N_NODES && (unsigned)dst < N_NODES) {
                unsigned int w = ldbf(ew, e, isf);
                unsigned int pos = atomicAdd(&cur[dst >> 8], 1u);
                uint2 r; r.x = (w << 16) | (unsigned)src; r.y = (unsigned)dst;
                rec[pos] = r;
            }
        }
    }
}

// ---------------- radix CSR fill 2: per-bucket sub-sort -> row_ptr + final cw ----------------
__global__ __launch_bounds__(512) void f2_kernel(const uint2* __restrict__ rec,
                                                 const unsigned int* __restrict__ btot,
                                                 int* __restrict__ rp, unsigned int* __restrict__ cw) {
    __shared__ unsigned int sb[256], c2[256], sc[256], cur2[256];
    int tid = threadIdx.x, b = blockIdx.x;
    unsigned int vb = 0;
    if (tid < 256) { vb = (tid < NBKT) ? btot[tid] : 0u; sb[tid] = vb; }
    __syncthreads();
    for (int off = 1; off < 256; off <<= 1) {
        unsigned int t = (tid < 256 && tid >= off) ? sb[tid - off] : 0u;
        __syncthreads();
        if (tid < 256) sb[tid] += t;
        __syncthreads();
    }
    unsigned int s0 = (b > 0) ? sb[b - 1] : 0u;
    unsigned int e0 = sb[b];
    if (b == 0 && tid == 0) rp[N_NODES] = (int)sb[NBKT - 1];
    if (tid < 256) c2[tid] = 0;
    __syncthreads();
    for (unsigned int pos = s0 + tid; pos < e0; pos += 512)
        atomicAdd(&c2[rec[pos].y & 255u], 1u);
    __syncthreads();
    unsigned int v = 0;
    if (tid < 256) { v = c2[tid]; sc[tid] = v; }
    __syncthreads();
    for (int off = 1; off < 256; off <<= 1) {
        unsigned int t = (tid < 256 && tid >= off) ? sc[tid - off] : 0u;
        __syncthreads();
        if (tid < 256) sc[tid] += t;
        __syncthreads();
    }
    if (tid < 256) {
        unsigned int start = s0 + sc[tid] - v;
        int node = b * 256 + tid;
        if (node < N_NODES) rp[node] = (int)start;
        cur2[tid] = start;
    }
    __syncthreads();
    for (unsigned int pos = s0 + tid; pos < e0; pos += 512) {
        uint2 r = rec[pos];
        unsigned int p = atomicAdd(&cur2[r.y & 255u], 1u);
        cw[p] = r.x;
    }
}

// ---------------- fallback: zero output ----------------
__global__ __launch_bounds__(256) void zout_kernel(unsigned short* __restrict__ out, long n) {
    long t = (long)blockIdx.x * 256 + threadIdx.x;
    if (t < n) out[t] = 0;
}

// ---------------- agg1 v3: LDS-staged edge records, 16 lanes/node x 16B, 4 nodes/wave ----------------
// Each wave owns 4 consecutive nodes -> contiguous cw slice (Poisson(64)); staged into LDS so
// the edge loop's critical chain is LDS-broadcast -> gather -> FMA (no HBM load, no shuffle).
__global__ __launch_bounds__(256) void agg1_kernel(const unsigned short* __restrict__ x0raw,
                                                   const unsigned short* __restrict__ x0conv,
                                                   int use_conv, const int* __restrict__ flags,
                                                   const int* __restrict__ rp, const unsigned int* __restrict__ cw,
                                                   unsigned short* __restrict__ X12) {
    __shared__ unsigned int erec[4][256];
    const unsigned short* x0b = (use_conv && flags[0]) ? x0conv : x0raw;
    int wv = threadIdx.x >> 6;
    int lane = threadIdx.x & 63;
    int l = lane & 15;
    int r0 = blockIdx.x * 16 + wv * 4;       // 3125*16 == N_NODES exactly
    int s0 = rp[r0], e4 = rp[r0 + 4];
    if (s0 < 0) s0 = 0;
    if (e4 > N_EDGES) e4 = N_EDGES;
    if (e4 < s0) e4 = s0;
    int span = e4 - s0;
    int staged = (span <= 256);
    if (staged) {
        for (int i = lane; i < span; i += 64)
            erec[wv][i] = __builtin_nontemporal_load(cw + s0 + i);
    }
    __syncthreads();
    int r = r0 + (lane >> 4);
    int js = rp[r], je = rp[r + 1];
    if (js < s0) js = s0;
    if (je > e4) je = e4;
    float a0 = 0.f, a1 = 0.f, a2 = 0.f, a3 = 0.f;
    float a4 = 0.f, a5 = 0.f, a6 = 0.f, a7 = 0.f;
    if (staged) {
        int jb = js - s0, jeR = je - s0;
        for (int j = jb; j < jeR; j += 8) {
            int m = jeR - j; if (m > 8) m = 8;
            unsigned int vv[8]; u32x4 q[8];
#pragma unroll
            for (int u = 0; u < 8; u++) if (u < m) vv[u] = erec[wv][j + u];
#pragma unroll
            for (int u = 0; u < 8; u++) if (u < m)
                q[u] = *(const u32x4*)(x0b + (long)(vv[u] & 0xFFFFu) * 128 + l * 8);
#pragma unroll
            for (int u = 0; u < 8; u++) if (u < m) {
                float w = bf2f((unsigned short)(vv[u] >> 16));
                a0 += w * bf2f((unsigned short)(q[u][0] & 0xffffu));
                a1 += w * bf2f((unsigned short)(q[u][0] >> 16));
                a2 += w * bf2f((unsigned short)(q[u][1] & 0xffffu));
                a3 += w * bf2f((unsigned short)(q[u][1] >> 16));
                a4 += w * bf2f((unsigned short)(q[u][2] & 0xffffu));
                a5 += w * bf2f((unsigned short)(q[u][2] >> 16));
                a6 += w * bf2f((unsigned short)(q[u][3] & 0xffffu));
                a7 += w * bf2f((unsigned short)(q[u][3] >> 16));
            }
        }
    } else {
        for (int j = js; j < je; j += 8) {
            int m = je - j; if (m > 8) m = 8;
            unsigned int vv[8]; u32x4 q[8];
#pragma unroll
            for (int u = 0; u < 8; u++) if (u < m) vv[u] = __builtin_nontemporal_load(cw + j + u);
#pragma unroll
            for (int u = 0; u < 8; u++) if (u < m)
                q[u] = *(const u32x4*)(x0b + (long)(vv[u] & 0xFFFFu) * 128 + l * 8);
#pragma unroll
            for (int u = 0; u < 8; u++) if (u < m) {
                float w = bf2f((unsigned short)(vv[u] >> 16));
                a0 += w * bf2f((unsigned short)(q[u][0] & 0xffffu));
                a1 += w * bf2f((unsigned short)(q[u][0] >> 16));
                a2 += w * bf2f((unsigned short)(q[u][1] & 0xffffu));
                a3 += w * bf2f((unsigned short)(q[u][1] >> 16));
                a4 += w * bf2f((unsigned short)(q[u][2] & 0xffffu));
                a5 += w * bf2f((unsigned short)(q[u][2] >> 16));
                a6 += w * bf2f((unsigned short)(q[u][3] & 0xffffu));
                a7 += w * bf2f((unsigned short)(q[u][3] >> 16));
            }
        }
    }
    u32x4 pk;
    pk[0] = (unsigned int)f2bf(a0) | ((unsigned int)f2bf(a1) << 16);
    pk[1] = (unsigned int)f2bf(a2) | ((unsigned int)f2bf(a3) << 16);
    pk[2] = (unsigned int)f2bf(a4) | ((unsigned int)f2bf(a5) << 16);
    pk[3] = (unsigned int)f2bf(a6) | ((unsigned int)f2bf(a7) << 16);
    *(u32x4*)&X12[(long)r * 512 + 256 + l * 8] = pk;
}

// ---------------- agg2 v3: quartered + XCD-pinned + LDS-staged records, 4 lanes/node x 16B ----------------
// x1f8q region q (3.2MB contiguous) = ch q*64..q*64+63, 64B/node; bid%8 in {q,q+4} keeps it
// XCD-L2-resident (confirmed R7: FETCH 101->25MB). v3 stages each wave's contiguous cw slice
// (16 nodes, Poisson(256)) into LDS so the edge loop is LDS-broadcast -> L2 gather -> FMA.
__global__ __launch_bounds__(256) void agg2_kernel(const int* __restrict__ rp, const unsigned int* __restrict__ cw,
                                                   unsigned short* __restrict__ X12,
                                                   const unsigned char* __restrict__ x1f8q,
                                                   const int* __restrict__ flags, int f8mode) {
    __shared__ unsigned int erec[4][512];
    int usef8 = (f8mode == 2) || (f8mode == 1 && flags[0] == 0);
    int bid = blockIdx.x;
    int qq = bid & 3;
    int chunk = bid >> 2;
    int wv = threadIdx.x >> 6;
    int lane = threadIdx.x & 63;
    int sub = lane & 3;
    int r0 = chunk * 64 + wv * 16;
    int r0c = r0 < N_NODES ? r0 : N_NODES;
    int r4c = (r0 + 16) < N_NODES ? (r0 + 16) : N_NODES;
    int s0 = rp[r0c], e16 = rp[r4c];
    if (s0 < 0) s0 = 0;
    if (e16 > N_EDGES) e16 = N_EDGES;
    if (e16 < s0) e16 = s0;
    int span = e16 - s0;
    int staged = (span <= 512);
    if (staged) {
        for (int i = lane; i < span; i += 64)
            erec[wv][i] = __builtin_nontemporal_load(cw + s0 + i);
    }
    __syncthreads();
    int r = r0 + (lane >> 2);
    if (r >= N_NODES) return;
    int js = rp[r], je = rp[r + 1];
    if (js < s0) js = s0;
    if (je > e16) je = e16;
    float a[16];
#pragma unroll
    for (int c = 0; c < 16; c++) a[c] = 0.f;
    if (usef8) {
        const unsigned char* tab = x1f8q + (long)qq * QSZ + sub * 16;
        if (staged) {
            int jb = js - s0, jeR = je - s0;
            for (int j = jb; j < jeR; j += 8) {
                int m = jeR - j; if (m > 8) m = 8;
                unsigned int vv[8]; u32x4 q[8];
#pragma unroll
                for (int u = 0; u < 8; u++) if (u < m) vv[u] = erec[wv][j + u];
#pragma unroll
                for (int u = 0; u < 8; u++) if (u < m)
                    q[u] = *(const u32x4*)(tab + (vv[u] & 0xFFFFu) * 64);
#pragma unroll
                for (int u = 0; u < 8; u++) if (u < m) {
                    float w = bf2f((unsigned short)(vv[u] >> 16));
#pragma unroll
                    for (int c = 0; c < 4; c++) {
                        f32x2 plo = __builtin_amdgcn_cvt_pk_f32_fp8((int)q[u][c], false);
                        f32x2 phi = __builtin_amdgcn_cvt_pk_f32_fp8((int)q[u][c], true);
                        a[c * 4 + 0] += w * plo.x; a[c * 4 + 1] += w * plo.y;
                        a[c * 4 + 2] += w * phi.x; a[c * 4 + 3] += w * phi.y;
                    }
                }
            }
        } else {
            for (int j = js; j < je; j += 8) {
                int m = je - j; if (m > 8) m = 8;
                unsigned int vv[8]; u32x4 q[8];
#pragma unroll
                for (int u = 0; u < 8; u++) if (u < m) vv[u] = __builtin_nontemporal_load(cw + j + u);
#pragma unroll
                for (int u = 0; u < 8; u++) if (u < m)
                    q[u] = *(const u32x4*)(tab + (vv[u] & 0xFFFFu) * 64);
#pragma unroll
                for (int u = 0; u < 8; u++) if (u < m) {
                    float w = bf2f((unsigned short)(vv[u] >> 16));
#pragma unroll
                    for (int c = 0; c < 4; c++) {
                        f32x2 plo = __builtin_amdgcn_cvt_pk_f32_fp8((int)q[u][c], false);
                        f32x2 phi = __builtin_amdgcn_cvt_pk_f32_fp8((int)q[u][c], true);
                        a[c * 4 + 0] += w * plo.x; a[c * 4 + 1] += w * plo.y;
                        a[c * 4 + 2] += w * phi.x; a[c * 4 + 3] += w * phi.y;
                    }
                }
            }
        }
    } else {
        // bf16 fallback: 16 ch = 32B from X12 rows (x1 = cols 0..255)
        const unsigned short* tabb = X12 + qq * 64 + sub * 16;
        if (staged) {
            int jb = js - s0, jeR = je - s0;
            for (int j = jb; j < jeR; j += 8) {
                int m = jeR - j; if (m > 8) m = 8;
                unsigned int vv[8]; u32x4 q0[8], q1[8];
#pragma unroll
                for (int u = 0; u < 8; u++) if (u < m) vv[u] = erec[wv][j + u];
#pragma unroll
                for (int u = 0; u < 8; u++) if (u < m) {
                    const unsigned short* sp = tabb + (long)(vv[u] & 0xFFFFu) * 512;
                    q0[u] = *(const u32x4*)sp;
                    q1[u] = *(const u32x4*)(sp + 8);
                }
#pragma unroll
                for (int u = 0; u < 8; u++) if (u < m) {
                    float w = bf2f((unsigned short)(vv[u] >> 16));
#pragma unroll
                    for (int c = 0; c < 4; c++) {
                        a[c * 2 + 0] += w * bf2f((unsigned short)(q0[u][c] & 0xffffu));
                        a[c * 2 + 1] += w * bf2f((unsigned short)(q0[u][c] >> 16));
                        a[8 + c * 2 + 0] += w * bf2f((unsigned short)(q1[u][c] & 0xffffu));
                        a[8 + c * 2 + 1] += w * bf2f((unsigned short)(q1[u][c] >> 16));
                    }
                }
            }
        } else {
            for (int j = js; j < je; j += 8) {
                int m = je - j; if (m > 8) m = 8;
                unsigned int vv[8]; u32x4 q0[8], q1[8];
#pragma unroll
                for (int u = 0; u < 8; u++) if (u < m) vv[u] = __builtin_nontemporal_load(cw + j + u);
#pragma unroll
                for (int u = 0; u < 8; u++) if (u < m) {
                    const unsigned short* sp = tabb + (long)(vv[u] & 0xFFFFu) * 512;
                    q0[u] = *(const u32x4*)sp;
                    q1[u] = *(const u32x4*)(sp + 8);
                }
#pragma unroll
                for (int u = 0; u < 8; u++) if (u < m) {
                    float w = bf2f((unsigned short)(vv[u] >> 16));
#pragma unroll
                    for (int c = 0; c < 4; c++) {
                        a[c * 2 + 0] += w * bf2f((unsigned short)(q0[u][c] & 0xffffu));
                        a[c * 2 + 1] += w * bf2f((unsigned short)(q0[u][c] >> 16));
                        a[8 + c * 2 + 0] += w * bf2f((unsigned short)(q1[u][c] & 0xffffu));
                        a[8 + c * 2 + 1] += w * bf2f((unsigned short)(q1[u][c] >> 16));
                    }
                }
            }
        }
    }
    u32x4 p0, p1;
#pragma unroll
    for (int c = 0; c < 4; c++) {
        p0[c] = (unsigned int)f2bf(a[c * 2]) | ((unsigned int)f2bf(a[c * 2 + 1]) << 16);
        p1[c] = (unsigned int)f2bf(a[8 + c * 2]) | ((unsigned int)f2bf(a[8 + c * 2 + 1]) << 16);
    }
    unsigned short* op = &X12[(long)r * 512 + 256 + qq * 64 + sub * 16];
    *(u32x4*)op = p0;
    *(u32x4*)(op + 8) = p1;
}

// ---------------- big MFMA GEMM: 128x256 tile, 512 thr (8 waves, 2x4) ----------------
__global__ __launch_bounds__(512) void gemm_big_kernel(
    const unsigned short* __restrict__ Aagg, int lda_agg, int Kagg,
    const unsigned short* __restrict__ AxRaw, const unsigned short* __restrict__ AxConv,
    int use_conv, int lda_x,
    const unsigned short* __restrict__ Bt, int K,
    const float* __restrict__ bias, const int* __restrict__ flags,
    unsigned short* __restrict__ out, int ldo, int ocol, int M,
    unsigned char* __restrict__ x1f8q, int f8mode) {
    __shared__ __align__(16) unsigned short As[128][64];   // 16 KB, 128 B/row
    __shared__ __align__(16) unsigned short Bs[256][64];   // 32 KB
    const unsigned short* Ax = (use_conv && flags[0]) ? AxConv : AxRaw;
    int dof8 = (f8mode == 2) || (f8mode == 1 && flags[0] == 0);
    int tid = threadIdx.x;
    int bm0 = blockIdx.x * 128;
    int wave = tid >> 6, lane = tid & 63;
    int wm = wave >> 2, wn = wave & 3;
    int quad = lane >> 4, l16 = lane & 15;
    int lr = lane >> 3;            // row within 8-row chunk (0..7)
    int sc = (lane & 7) ^ lr;      // source chunk for this lane's dest slot

    f32x4 acc[4][4];
#pragma unroll
    for (int mt = 0; mt < 4; mt++)
#pragma unroll
        for (int nt = 0; nt < 4; nt++) acc[mt][nt] = (f32x4){0.f, 0.f, 0.f, 0.f};

    for (int k0 = 0; k0 < K; k0 += 64) {
        const unsigned short* srcp;
        int stride, koff;
        if (k0 < Kagg) { srcp = Aagg; stride = lda_agg; koff = k0; }
        else           { srcp = Ax;   stride = lda_x;   koff = k0 - Kagg; }
        // A tile: 16 chunks of 1 KB (8 rows x 128 B each); wave covers 2
#pragma unroll
        for (int i = 0; i < 2; i++) {
            int t = wave * 2 + i;
            int r = t * 8 + lr;
            int gr = bm0 + r; if (gr >= M) gr = M - 1;
            cp16(srcp + (long)gr * stride + koff + sc * 8, (char*)As + t * 1024);
        }
        // B tile: 32 chunks; wave covers 4
#pragma unroll
        for (int i = 0; i < 4; i++) {
            int t = wave * 4 + i;
            int r = t * 8 + lr;
            cp16(Bt + (long)r * K + k0 + sc * 8, (char*)Bs + t * 1024);
        }
        __syncthreads();
#pragma unroll
        for (int kc = 0; kc < 64; kc += 32) {
            int k8 = (kc >> 3) + quad;          // source chunk within K-step
            int swz = (k8 ^ (l16 & 7)) << 4;    // swizzled byte offset of that chunk
            bf16x8 a[4], b[4];
#pragma unroll
            for (int mt = 0; mt < 4; mt++) {
                int row = wm * 64 + mt * 16 + l16;
                a[mt] = *(const bf16x8*)((const char*)As + row * 128 + swz);
            }
#pragma unroll
            for (int nt = 0; nt < 4; nt++) {
                int row = wn * 64 + nt * 16 + l16;
                b[nt] = *(const bf16x8*)((const char*)Bs + row * 128 + swz);
            }
#pragma unroll
            for (int mt = 0; mt < 4; mt++)
#pragma unroll
                for (int nt = 0; nt < 4; nt++)
                    acc[mt][nt] = __builtin_amdgcn_mfma_f32_16x16x32_bf16(a[mt], b[nt], acc[mt][nt], 0, 0, 0);
        }
        __syncthreads();
    }

#pragma unroll
    for (int mt = 0; mt < 4; mt++) {
#pragma unroll
        for (int nt = 0; nt < 4; nt++) {
            f32x4 a = acc[mt][nt];
            int colI = wn * 64 + nt * 16 + l16;
            float bv = bias[colI];
#pragma unroll
            for (int rr = 0; rr < 4; rr++) {
                int row = bm0 + wm * 64 + mt * 16 + quad * 4 + rr;
                if (row < M) {
                    float v = a[rr] + bv;
                    v = v > 0.f ? v : 0.f;
                    out[(long)row * ldo + ocol + colI] = f2bf(v);
                    if (dof8) {
                        // quarter-major fp8: region (colI>>6), 64B/node
                        int p = __builtin_amdgcn_cvt_pk_fp8_f32(v, v, 0, false);
                        x1f8q[(long)(colI >> 6) * QSZ + (long)row * 64 + (colI & 63)] =
                            (unsigned char)(p & 0xff);
                    }
                }
            }
        }
    }
}

// ---------------- head GEMM: 64 rows, TN=2, dtype follows input ----------------
__global__ __launch_bounds__(256) void gemm_head_kernel(
    const unsigned short* __restrict__ Ax, int lda_x,
    const unsigned short* __restrict__ Bt, int K,
    const float* __restrict__ bias,
    void* __restrict__ out, int ldo,
    int M, int realN, const int* __restrict__ flagF) {
    __shared__ __align__(16) unsigned short As[64][64];   // 8 KB
    __shared__ __align__(16) unsigned short Bs[64][64];   // 8 KB
    int tid = threadIdx.x;
    int bm0 = blockIdx.x * 64;
    int wave = tid >> 6, lane = tid & 63;
    int wm = wave >> 1, wn = wave & 1;
    int quad = lane >> 4, l16 = lane & 15;
    int lr = lane >> 3;
    int sc = (lane & 7) ^ lr;

    f32x4 acc[2][2];
#pragma unroll
    for (int mt = 0; mt < 2; mt++)
#pragma unroll
        for (int nt = 0; nt < 2; nt++) acc[mt][nt] = (f32x4){0.f, 0.f, 0.f, 0.f};

    for (int k0 = 0; k0 < K; k0 += 64) {
#pragma unroll
        for (int i = 0; i < 2; i++) {
            int t = wave * 2 + i;
            int r = t * 8 + lr;
            int gr = bm0 + r; if (gr >= M) gr = M - 1;
            cp16(Ax + (long)gr * lda_x + k0 + sc * 8, (char*)As + t * 1024);
        }
#pragma unroll
        for (int i = 0; i < 2; i++) {
            int t = wave * 2 + i;
            int r = t * 8 + lr;
            cp16(Bt + (long)r * K + k0 + sc * 8, (char*)Bs + t * 1024);
        }
        __syncthreads();
#pragma unroll
        for (int kc = 0; kc < 64; kc += 32) {
            int k8 = (kc >> 3) + quad;
            int swz = (k8 ^ (l16 & 7)) << 4;
            bf16x8 a0 = *(const bf16x8*)((const char*)As + (wm * 32 + l16) * 128 + swz);
            bf16x8 a1 = *(const bf16x8*)((const char*)As + (wm * 32 + 16 + l16) * 128 + swz);
#pragma unroll
            for (int nt = 0; nt < 2; nt++) {
                bf16x8 b = *(const bf16x8*)((const char*)Bs + (wn * 32 + nt * 16 + l16) * 128 + swz);
                acc[0][nt] = __builtin_amdgcn_mfma_f32_16x16x32_bf16(a0, b, acc[0][nt], 0, 0, 0);
                acc[1][nt] = __builtin_amdgcn_mfma_f32_16x16x32_bf16(a1, b, acc[1][nt], 0, 0, 0);
            }
        }
        __syncthreads();
    }

    int out_f32 = *flagF;
#pragma unroll
    for (int mt = 0; mt < 2; mt++) {
#pragma unroll
        for (int nt = 0; nt < 2; nt++) {
            f32x4 a = acc[mt][nt];
            int colI = wn * 32 + nt * 16 + l16;
            float bv = bias[colI];
#pragma unroll
            for (int rr = 0; rr < 4; rr++) {
                int row = bm0 + wm * 32 + mt * 16 + quad * 4 + rr;
                if (row < M && colI < realN) {
                    float v = a[rr] + bv;
                    long idx = (long)row * ldo + colI;
                    if (out_f32) ((float*)out)[idx] = v;
                    else ((unsigned short*)out)[idx] = f2bf(v);
                }
            }
        }
    }
}

extern "C" void kernel_launch(void* const* d_in, const int* in_sizes, int n_in,
                              void* d_out, int out_size, void* d_ws, size_t ws_size,
                              hipStream_t stream) {
    const void* x0  = d_in[0];
    const int*  ei  = (const int*)d_in[1];
    const void* ew  = d_in[2];
    const void* w1r = d_in[3];
    const void* b1h = d_in[4];
    const void* w1x = d_in[5];
    const void* w2r = d_in[6];
    const void* b2h = d_in[7];
    const void* w2x = d_in[8];
    const void* lw  = d_in[9];
    const void* lbh = d_in[10];

    // ---- workspace layout ----
    char* ws = (char*)d_ws;
    unsigned short* X12     = (unsigned short*)(ws);             // 51,200,000  [N x 512]
    unsigned int*   cw      = (unsigned int*)(ws + 51200000);    //  3,200,000
    int*            row_ptr = (int*)(ws + 54400000);             //    200,064
    unsigned short* Bt1     = (unsigned short*)(ws + 54800128);  //    131,072
    unsigned short* Bt2     = (unsigned short*)(ws + 54931200);  //    262,144
    unsigned short* Bt3     = (unsigned short*)(ws + 55193344);  //     65,536
    float*          b1      = (float*)(ws + 55258880);           //      1,024
    float*          b2      = (float*)(ws + 55259904);           //      1,024
    float*          b3      = (float*)(ws + 55260928);           //        256
    int*            flags   = (int*)(ws + 55261184);             //         64
    unsigned short* x0bf    = (unsigned short*)(ws + 55262272);  // 12,800,000 (fp32-input conv)
    unsigned char*  x1f8sep = (unsigned char*)(ws + 68062272);   // 12,800,000 (fp8 x1, quarter-major)
    const size_t NEED_NOCONV = 55262272;
    const size_t NEED_FULL   = 68062272;  // + x0bf
    const size_t NEED_F8SEP  = 80862272;  // + separate x1f8

    // ---- radix-CSR scratch: lives inside X12, which is dead until agg1 ----
    uint2*        rec   = (uint2*)(ws);                          // 6,400,000 (<= E*8)
    unsigned int* bc    = (unsigned int*)(ws + 6400000);         // HB*NBKT*4 = 613,088
    unsigned int* pbse  = (unsigned int*)(ws + 7013120);         // 613,088
    unsigned int* btot  = (unsigned int*)(ws + 7626240);         // 1,024

    if (ws_size < NEED_NOCONV) {
        long n = (long)N_NODES * OUTC;
        zout_kernel<<<(int)((n + 255) / 256), 256, 0, stream>>>((unsigned short*)d_out, n);
        return;
    }
    int use_conv = (ws_size >= NEED_FULL) ? 1 : 0;
    // f8mode: 2 = separate buffer (always usable); 1 = alias x0bf (usable iff input bf16); 0 = off
    int f8mode = (ws_size >= NEED_F8SEP) ? 2 : (use_conv ? 1 : 0);
    unsigned char* x1f8 = (f8mode == 2) ? x1f8sep : (unsigned char*)x0bf;

    int* flagF = flags + 0;

    init_kernel<<<2, 256, 0, stream>>>((const unsigned int*)x0, flags, ei);

    int cb = use_conv ? ((N_NODES * IN_CH) / (256 * 8)) : 0;  // 3125 vectorized conv blocks
    {
        int ptotal = 256 * 256 + 256 * 512 + 64 * 512 + 256 + 256 + 64;
        int pblocks = (ptotal + 255) / 256;  // 899
        prep_all_kernel<<<cb + pblocks + HB, 256, 0, stream>>>(
            x0, cb, w1r, w1x, w2r, w2x, lw, b1h, b2h, lbh, flags, x0bf,
            Bt1, Bt2, Bt3, b1, b2, b3, ei, bc, pblocks);
    }

    // CSR build: two-level counting sort (LDS atomics only; no device-scope atomics)
    s1_kernel<<<NBKT, 1024, 0, stream>>>(bc, pbse, btot);
    f1_kernel<<<HB, 256, 0, stream>>>(ei, ew, flags, pbse, btot, rec);
    f2_kernel<<<NBKT, 512, 0, stream>>>(rec, btot, row_ptr, cw);

    int mblocks  = (N_NODES + 127) / 128;  // 391
    int hblocks  = (N_NODES + 63) / 64;    // 782
    int ablocks  = (N_NODES + 15) / 16;    // 3125

    const unsigned short* x0raw = (const unsigned short*)x0;

    // layer 1 (gemm epilogue emits quarter-major fp8 x1 when enabled)
    agg1_kernel<<<ablocks, 256, 0, stream>>>(x0raw, x0bf, use_conv, flags, row_ptr, cw, X12);
    gemm_big_kernel<<<mblocks, 512, 0, stream>>>(X12 + 256, 512, 128,
                                                 x0raw, x0bf, use_conv, IN_CH,
                                                 Bt1, 256, b1, flags,
                                                 X12, 512, 0, N_NODES, x1f8, f8mode);
    // layer-2 agg: XCD-pinned quarter-major fp8 gather, LDS-staged records (v3)
    agg2_kernel<<<ABLKQ, 256, 0, stream>>>(row_ptr, cw, X12, x1f8, flags, f8mode);
    gemm_big_kernel<<<mblocks, 512, 0, stream>>>(X12 + 256, 512, 256,
                                                 X12, X12, 0, 512,
                                                 Bt2, 512, b2, flags,
                                                 X12, 512, 256, N_NODES,
                                                 (unsigned char*)nullptr, 0);
    // head
    gemm_head_kernel<<<hblocks, 256, 0, stream>>>(X12, 512, Bt3, 512, b3,
                                                  d_out, OUTC, N_NODES, OUTC, flagF);
}

// Round 11
// 264.407 us; speedup vs baseline: 1.0564x; 1.0564x over previous
//
#include <hip/hip_runtime.h>
#include <hip/hip_bf16.h>

#define N_NODES 50000
#define N_EDGES 800000
#define IN_CH   128
#define HID     256
#define OUTC    51

typedef __attribute__((ext_vector_type(8))) short  bf16x8;
typedef __attribute__((ext_vector_type(4))) float  f32x4;
typedef __attribute__((ext_vector_type(2))) float  f32x2;
typedef __attribute__((ext_vector_type(4))) unsigned int u32x4;

__device__ __forceinline__ float bf2f(unsigned short u) {
    union { unsigned int i; float f; } v; v.i = ((unsigned int)u) << 16; return v.f;
}
__device__ __forceinline__ unsigned short f2bf(float f) {
    union { float f; unsigned int i; } v; v.f = f;
    unsigned int u = v.i;
    unsigned int r = (u + 0x7fffu + ((u >> 16) & 1u)) >> 16;  // RNE
    return (unsigned short)r;
}
__device__ __forceinline__ unsigned short ldbf(const void* p, long i, int isf) {
    return isf ? f2bf(((const float*)p)[i]) : ((const unsigned short*)p)[i];
}
__device__ __forceinline__ float ldf(const void* p, long i, int isf) {
    return isf ? ((const float*)p)[i] : bf2f(((const unsigned short*)p)[i]);
}
__device__ __forceinline__ void load_edge_nt(const int* __restrict__ ei, int e, int is64,
                                             int* src, int* dst) {
    if (is64) { *src = __builtin_nontemporal_load(ei + 2 * e);
                *dst = __builtin_nontemporal_load(ei + 2 * (N_EDGES + e)); }
    else      { *src = __builtin_nontemporal_load(ei + e);
                *dst = __builtin_nontemporal_load(ei + N_EDGES + e); }
}

// async global->LDS 16B: wave-uniform LDS base, per-lane global src, HW dest = base + lane*16
typedef const __attribute__((address_space(1))) unsigned int* gas_u32;
typedef __attribute__((address_space(3))) unsigned int* las_u32;
__device__ __forceinline__ void cp16(const void* g, void* l) {
    __builtin_amdgcn_global_load_lds((gas_u32)g, (las_u32)l, 16, 0, 0);
}

// ---- radix-CSR constants ----
#define EBLK 1024                                // edges per histogram/fill block
#define HB   ((N_EDGES + EBLK - 1) / EBLK)       // 782 blocks
#define NBKT ((N_NODES + 255) / 256)             // 196 buckets of 256 nodes

// ---------------- init: dtype probe + int64 detect (device probe is MANDATORY:
// in_sizes may be element counts, and fp32 vs bf16 have identical counts) ----------------
__global__ __launch_bounds__(256) void init_kernel(const unsigned int* __restrict__ x0w,
                                                   int* __restrict__ flags,
                                                   const int* __restrict__ ei) {
    int tid = threadIdx.x;
    if (blockIdx.x == 0) {
        if (tid < 64) {
            unsigned int w = x0w[tid];
            unsigned int ex = (w >> 7) & 0xFFu;
            unsigned long long bm = __ballot(ex >= 0x60u && ex <= 0x90u);
            if (tid == 0) flags[0] = (__popcll(bm) >= 48) ? 0 : 1;
        }
        return;
    }
    __shared__ int any;
    if (tid == 0) any = 0;
    __syncthreads();
    int acc = 0;
    for (int s = 0; s < 8; s++) {
        int i = (tid * 8 + s) * (N_EDGES / 2048);
        acc |= ei[2 * i + 1];
    }
    if (acc != 0) any = 1;
    __syncthreads();
    if (tid == 0) flags[1] = any;
}

// ---------------- prep_all: x0 convert (fp32 only, 8 elem/thr) + weight prep + edge histogram ----------------
__global__ void prep_all_kernel(const void* __restrict__ x0, int cb,
                                const void* __restrict__ w1r, const void* __restrict__ w1x,
                                const void* __restrict__ w2r, const void* __restrict__ w2x,
                                const void* __restrict__ lw,
                                const void* __restrict__ b1h, const void* __restrict__ b2h,
                                const void* __restrict__ lbh, const int* __restrict__ flags,
                                unsigned short* __restrict__ x0bf,
                                unsigned short* __restrict__ Bt1, unsigned short* __restrict__ Bt2,
                                unsigned short* __restrict__ Bt3,
                                float* __restrict__ b1, float* __restrict__ b2, float* __restrict__ b3,
                                const int* __restrict__ ei, unsigned int* __restrict__ bc,
                                int pblocks) {
    __shared__ unsigned int cnt[NBKT];
    int isf = flags[0];
    if ((int)blockIdx.x < cb) {
        if (!isf) return;  // bf16 input: skip copy
        long t0 = ((long)blockIdx.x * 256 + threadIdx.x) * 8;   // cb*256*8 == N*IN_CH exactly
        const float* xf = (const float*)x0;
        f32x4 v0 = *(const f32x4*)(xf + t0);
        f32x4 v1 = *(const f32x4*)(xf + t0 + 4);
        u32x4 pk;
        pk[0] = (unsigned int)f2bf(v0[0]) | ((unsigned int)f2bf(v0[1]) << 16);
        pk[1] = (unsigned int)f2bf(v0[2]) | ((unsigned int)f2bf(v0[3]) << 16);
        pk[2] = (unsigned int)f2bf(v1[0]) | ((unsigned int)f2bf(v1[1]) << 16);
        pk[3] = (unsigned int)f2bf(v1[2]) | ((unsigned int)f2bf(v1[3]) << 16);
        *(u32x4*)(x0bf + t0) = pk;
        return;
    }
    int rb = blockIdx.x - cb;
    if (rb >= pblocks) {
        // ---- histogram block ----
        int b = rb - pblocks;
        int tid = threadIdx.x;
        if (tid < NBKT) cnt[tid] = 0;
        __syncthreads();
        int is64 = (flags[1] == 0);
        int e0 = b * EBLK;
#pragma unroll
        for (int u = 0; u < 4; u++) {
            int e = e0 + u * 256 + tid;
            if (e < N_EDGES) {
                int src, dst; load_edge_nt(ei, e, is64, &src, &dst);
                if ((unsigned)src < N_NODES && (unsigned)dst < N_NODES)
                    atomicAdd(&cnt[dst >> 8], 1u);
            }
        }
        __syncthreads();
        if (tid < NBKT) bc[tid * HB + b] = cnt[tid];  // [bucket][block]
        return;
    }
    int t = rb * 256 + threadIdx.x;
    if (t < 256 * 256) {
        int n = t >> 8, k = t & 255;
        Bt1[n * 256 + k] = (k < 128) ? ldbf(w1r, k * 256 + n, isf) : ldbf(w1x, (k - 128) * 256 + n, isf);
        return;
    }
    t -= 256 * 256;
    if (t < 256 * 512) {
        int n = t >> 9, k = t & 511;
        Bt2[n * 512 + k] = (k < 256) ? ldbf(w2r, k * 256 + n, isf) : ldbf(w2x, (k - 256) * 256 + n, isf);
        return;
    }
    t -= 256 * 512;
    if (t < 64 * 512) {
        int n = t >> 9, k = t & 511;
        Bt3[n * 512 + k] = (n < OUTC) ? ldbf(lw, k * OUTC + n, isf) : (unsigned short)0;
        return;
    }
    t -= 64 * 512;
    if (t < 256) { b1[t] = ldf(b1h, t, isf); return; }
    t -= 256;
    if (t < 256) { b2[t] = ldf(b2h, t, isf); return; }
    t -= 256;
    if (t < 64)  { b3[t] = (t < OUTC) ? ldf(lbh, t, isf) : 0.0f; return; }
}

// ---------------- radix CSR scan 1: per-bucket prefix over blocks ----------------
__global__ __launch_bounds__(1024) void s1_kernel(const unsigned int* __restrict__ bc,
                                                  unsigned int* __restrict__ pbase,
                                                  unsigned int* __restrict__ total) {
    __shared__ unsigned int sd[1024];
    int b = blockIdx.x, tid = threadIdx.x;
    unsigned int v = (tid < HB) ? bc[b * HB + tid] : 0u;
    sd[tid] = v;
    __syncthreads();
    for (int off = 1; off < 1024; off <<= 1) {
        unsigned int t = (tid >= off) ? sd[tid - off] : 0u;
        __syncthreads();
        sd[tid] += t;
        __syncthreads();
    }
    if (tid < HB) pbase[tid * NBKT + b] = sd[tid] - v;  // [block][bucket], exclusive
    if (tid == 1023) total[b] = sd[1023];
}

// ---------------- radix CSR fill 1: scatter (w|src,dst) records into bucket regions ----------------
__global__ __launch_bounds__(256) void f1_kernel(const int* __restrict__ ei, const void* __restrict__ ew,
                                                 const int* __restrict__ flags,
                                                 const unsigned int* __restrict__ pbase,
                                                 const unsigned int* __restrict__ btot,
                                                 uint2* __restrict__ rec) {
    __shared__ unsigned int cur[NBKT];
    __shared__ unsigned int sb[256];
    int tid = threadIdx.x;
    unsigned int v = (tid < NBKT) ? btot[tid] : 0u;
    sb[tid] = v;
    __syncthreads();
    for (int off = 1; off < 256; off <<= 1) {
        unsigned int t = (tid >= off) ? sb[tid - off] : 0u;
        __syncthreads();
        sb[tid] += t;
        __syncthreads();
    }
    if (tid < NBKT) cur[tid] = (sb[tid] - v) + pbase[blockIdx.x * NBKT + tid];
    __syncthreads();
    int is64 = (flags[1] == 0);
    int isf = flags[0];
    int e0 = blockIdx.x * EBLK;
#pragma unroll
    for (int u = 0; u < 4; u++) {
        int e = e0 + u * 256 + tid;
        if (e < N_EDGES) {
            int src, dst; load_edge_nt(ei, e, is64, &src, &dst);
            if ((unsigned)src < N_NODES && (unsigned)dst < N_NODES) {
                unsigned int w = ldbf(ew, e, isf);
                unsigned int pos = atomicAdd(&cur[dst >> 8], 1u);
                uint2 r; r.x = (w << 16) | (unsigned)src; r.y = (unsigned)dst;
                rec[pos] = r;
            }
        }
    }
}

// ---------------- radix CSR fill 2: per-bucket sub-sort -> row_ptr + final cw ----------------
__global__ __launch_bounds__(512) void f2_kernel(const uint2* __restrict__ rec,
                                                 const unsigned int* __restrict__ btot,
                                                 int* __restrict__ rp, unsigned int* __restrict__ cw) {
    __shared__ unsigned int sb[256], c2[256], sc[256], cur2[256];
    int tid = threadIdx.x, b = blockIdx.x;
    unsigned int vb = 0;
    if (tid < 256) { vb = (tid < NBKT) ? btot[tid] : 0u; sb[tid] = vb; }
    __syncthreads();
    for (int off = 1; off < 256; off <<= 1) {
        unsigned int t = (tid < 256 && tid >= off) ? sb[tid - off] : 0u;
        __syncthreads();
        if (tid < 256) sb[tid] += t;
        __syncthreads();
    }
    unsigned int s0 = (b > 0) ? sb[b - 1] : 0u;
    unsigned int e0 = sb[b];
    if (b == 0 && tid == 0) rp[N_NODES] = (int)sb[NBKT - 1];
    if (tid < 256) c2[tid] = 0;
    __syncthreads();
    for (unsigned int pos = s0 + tid; pos < e0; pos += 512)
        atomicAdd(&c2[rec[pos].y & 255u], 1u);
    __syncthreads();
    unsigned int v = 0;
    if (tid < 256) { v = c2[tid]; sc[tid] = v; }
    __syncthreads();
    for (int off = 1; off < 256; off <<= 1) {
        unsigned int t = (tid < 256 && tid >= off) ? sc[tid - off] : 0u;
        __syncthreads();
        if (tid < 256) sc[tid] += t;
        __syncthreads();
    }
    if (tid < 256) {
        unsigned int start = s0 + sc[tid] - v;
        int node = b * 256 + tid;
        if (node < N_NODES) rp[node] = (int)start;
        cur2[tid] = start;
    }
    __syncthreads();
    for (unsigned int pos = s0 + tid; pos < e0; pos += 512) {
        uint2 r = rec[pos];
        unsigned int p = atomicAdd(&cur2[r.y & 255u], 1u);
        cw[p] = r.x;
    }
}

// ---------------- fallback: zero output ----------------
__global__ __launch_bounds__(256) void zout_kernel(unsigned short* __restrict__ out, long n) {
    long t = (long)blockIdx.x * 256 + threadIdx.x;
    if (t < n) out[t] = 0;
}

// ---------------- agg1: 16 lanes/node x 16B (u32x4), 4 nodes/wave, bf16 (R3 best-known) ----------------
__global__ __launch_bounds__(256) void agg1_kernel(const unsigned short* __restrict__ x0raw,
                                                   const unsigned short* __restrict__ x0conv,
                                                   int use_conv, const int* __restrict__ flags,
                                                   const int* __restrict__ rp, const unsigned int* __restrict__ cw,
                                                   unsigned short* __restrict__ X12) {
    const unsigned short* x0b = (use_conv && flags[0]) ? x0conv : x0raw;
    int r = blockIdx.x * 16 + (threadIdx.x >> 4);
    if (r >= N_NODES) return;
    int l = threadIdx.x & 15;
    int grpbase = threadIdx.x & 48;   // 16-lane group base within wave
    int js = rp[r], je = rp[r + 1];
    if (js < 0) js = 0;
    if (je > N_EDGES) je = N_EDGES;
    float a0 = 0.f, a1 = 0.f, a2 = 0.f, a3 = 0.f;
    float a4 = 0.f, a5 = 0.f, a6 = 0.f, a7 = 0.f;
    for (int base = js; base < je; base += 16) {
        int n = je - base; if (n > 16) n = 16;
        int idx = base + l; if (idx >= je) idx = je - 1;
        unsigned int rec = __builtin_nontemporal_load(cw + idx);
        for (int j = 0; j < n; j += 4) {
            int m = n - j; if (m > 4) m = 4;
            unsigned int vv[4]; u32x4 q[4];
#pragma unroll
            for (int u = 0; u < 4; u++) vv[u] = __shfl(rec, grpbase + j + u);
#pragma unroll
            for (int u = 0; u < 4; u++) if (u < m)
                q[u] = *(const u32x4*)(x0b + (long)(vv[u] & 0xFFFFu) * 128 + l * 8);
#pragma unroll
            for (int u = 0; u < 4; u++) if (u < m) {
                float w = bf2f((unsigned short)(vv[u] >> 16));
                a0 += w * bf2f((unsigned short)(q[u][0] & 0xffffu));
                a1 += w * bf2f((unsigned short)(q[u][0] >> 16));
                a2 += w * bf2f((unsigned short)(q[u][1] & 0xffffu));
                a3 += w * bf2f((unsigned short)(q[u][1] >> 16));
                a4 += w * bf2f((unsigned short)(q[u][2] & 0xffffu));
                a5 += w * bf2f((unsigned short)(q[u][2] >> 16));
                a6 += w * bf2f((unsigned short)(q[u][3] & 0xffffu));
                a7 += w * bf2f((unsigned short)(q[u][3] >> 16));
            }
        }
    }
    u32x4 pk;
    pk[0] = (unsigned int)f2bf(a0) | ((unsigned int)f2bf(a1) << 16);
    pk[1] = (unsigned int)f2bf(a2) | ((unsigned int)f2bf(a3) << 16);
    pk[2] = (unsigned int)f2bf(a4) | ((unsigned int)f2bf(a5) << 16);
    pk[3] = (unsigned int)f2bf(a6) | ((unsigned int)f2bf(a7) << 16);
    *(u32x4*)&X12[(long)r * 512 + 256 + l * 8] = pk;
}

// ---------------- agg2: 16 lanes/node x 16B, fp8 (8 deep) or bf16 (4 deep) (R3 best-known) ----------------
__global__ __launch_bounds__(256) void agg2_kernel(const int* __restrict__ rp, const unsigned int* __restrict__ cw,
                                                   unsigned short* __restrict__ X12,
                                                   const unsigned char* __restrict__ x1f8,
                                                   const int* __restrict__ flags, int f8mode) {
    int usef8 = (f8mode == 2) || (f8mode == 1 && flags[0] == 0);
    int r = blockIdx.x * 16 + (threadIdx.x >> 4);
    if (r >= N_NODES) return;
    int l = threadIdx.x & 15;
    int grpbase = threadIdx.x & 48;
    int js = rp[r], je = rp[r + 1];
    if (js < 0) js = 0;
    if (je > N_EDGES) je = N_EDGES;
    float a[16];
#pragma unroll
    for (int c = 0; c < 16; c++) a[c] = 0.f;
    if (usef8) {
        for (int base = js; base < je; base += 16) {
            int n = je - base; if (n > 16) n = 16;
            int idx = base + l; if (idx >= je) idx = je - 1;
            unsigned int rec = __builtin_nontemporal_load(cw + idx);
            for (int j = 0; j < n; j += 8) {
                int m = n - j; if (m > 8) m = 8;
                unsigned int vv[8]; u32x4 q[8];
#pragma unroll
                for (int u = 0; u < 8; u++) vv[u] = __shfl(rec, grpbase + j + u);
#pragma unroll
                for (int u = 0; u < 8; u++) if (u < m)
                    q[u] = *(const u32x4*)(x1f8 + (long)(vv[u] & 0xFFFFu) * 256 + l * 16);
#pragma unroll
                for (int u = 0; u < 8; u++) if (u < m) {
                    float w = bf2f((unsigned short)(vv[u] >> 16));
#pragma unroll
                    for (int c = 0; c < 4; c++) {
                        f32x2 plo = __builtin_amdgcn_cvt_pk_f32_fp8((int)q[u][c], false);
                        f32x2 phi = __builtin_amdgcn_cvt_pk_f32_fp8((int)q[u][c], true);
                        a[c * 4 + 0] += w * plo.x; a[c * 4 + 1] += w * plo.y;
                        a[c * 4 + 2] += w * phi.x; a[c * 4 + 3] += w * phi.y;
                    }
                }
            }
        }
    } else {
        for (int base = js; base < je; base += 16) {
            int n = je - base; if (n > 16) n = 16;
            int idx = base + l; if (idx >= je) idx = je - 1;
            unsigned int rec = __builtin_nontemporal_load(cw + idx);
            for (int j = 0; j < n; j += 4) {
                int m = n - j; if (m > 4) m = 4;
                unsigned int vv[4]; u32x4 q0[4], q1[4];
#pragma unroll
                for (int u = 0; u < 4; u++) vv[u] = __shfl(rec, grpbase + j + u);
#pragma unroll
                for (int u = 0; u < 4; u++) if (u < m) {
                    const unsigned short* sp = X12 + (long)(vv[u] & 0xFFFFu) * 512 + l * 16;
                    q0[u] = *(const u32x4*)sp;
                    q1[u] = *(const u32x4*)(sp + 8);
                }
#pragma unroll
                for (int u = 0; u < 4; u++) if (u < m) {
                    float w = bf2f((unsigned short)(vv[u] >> 16));
#pragma unroll
                    for (int c = 0; c < 4; c++) {
                        a[c * 2 + 0] += w * bf2f((unsigned short)(q0[u][c] & 0xffffu));
                        a[c * 2 + 1] += w * bf2f((unsigned short)(q0[u][c] >> 16));
                        a[8 + c * 2 + 0] += w * bf2f((unsigned short)(q1[u][c] & 0xffffu));
                        a[8 + c * 2 + 1] += w * bf2f((unsigned short)(q1[u][c] >> 16));
                    }
                }
            }
        }
    }
    u32x4 p0, p1;
#pragma unroll
    for (int c = 0; c < 4; c++) {
        p0[c] = (unsigned int)f2bf(a[c * 2]) | ((unsigned int)f2bf(a[c * 2 + 1]) << 16);
        p1[c] = (unsigned int)f2bf(a[8 + c * 2]) | ((unsigned int)f2bf(a[8 + c * 2 + 1]) << 16);
    }
    unsigned short* op = &X12[(long)r * 512 + 256 + l * 16];
    *(u32x4*)op = p0;
    *(u32x4*)(op + 8) = p1;
}

// ---------------- big MFMA GEMM: 128x256 tile, 512 thr (8 waves, 2x4) ----------------
__global__ __launch_bounds__(512) void gemm_big_kernel(
    const unsigned short* __restrict__ Aagg, int lda_agg, int Kagg,
    const unsigned short* __restrict__ AxRaw, const unsigned short* __restrict__ AxConv,
    int use_conv, int lda_x,
    const unsigned short* __restrict__ Bt, int K,
    const float* __restrict__ bias, const int* __restrict__ flags,
    unsigned short* __restrict__ out, int ldo, int ocol, int M,
    unsigned char* __restrict__ x1f8, int f8mode) {
    __shared__ __align__(16) unsigned short As[128][64];   // 16 KB, 128 B/row
    __shared__ __align__(16) unsigned short Bs[256][64];   // 32 KB
    const unsigned short* Ax = (use_conv && flags[0]) ? AxConv : AxRaw;
    int dof8 = (f8mode == 2) || (f8mode == 1 && flags[0] == 0);
    int tid = threadIdx.x;
    int bm0 = blockIdx.x * 128;
    int wave = tid >> 6, lane = tid & 63;
    int wm = wave >> 2, wn = wave & 3;
    int quad = lane >> 4, l16 = lane & 15;
    int lr = lane >> 3;            // row within 8-row chunk (0..7)
    int sc = (lane & 7) ^ lr;      // source chunk for this lane's dest slot

    f32x4 acc[4][4];
#pragma unroll
    for (int mt = 0; mt < 4; mt++)
#pragma unroll
        for (int nt = 0; nt < 4; nt++) acc[mt][nt] = (f32x4){0.f, 0.f, 0.f, 0.f};

    for (int k0 = 0; k0 < K; k0 += 64) {
        const unsigned short* srcp;
        int stride, koff;
        if (k0 < Kagg) { srcp = Aagg; stride = lda_agg; koff = k0; }
        else           { srcp = Ax;   stride = lda_x;   koff = k0 - Kagg; }
        // A tile: 16 chunks of 1 KB (8 rows x 128 B each); wave covers 2
#pragma unroll
        for (int i = 0; i < 2; i++) {
            int t = wave * 2 + i;
            int r = t * 8 + lr;
            int gr = bm0 + r; if (gr >= M) gr = M - 1;
            cp16(srcp + (long)gr * stride + koff + sc * 8, (char*)As + t * 1024);
        }
        // B tile: 32 chunks; wave covers 4
#pragma unroll
        for (int i = 0; i < 4; i++) {
            int t = wave * 4 + i;
            int r = t * 8 + lr;
            cp16(Bt + (long)r * K + k0 + sc * 8, (char*)Bs + t * 1024);
        }
        __syncthreads();
#pragma unroll
        for (int kc = 0; kc < 64; kc += 32) {
            int k8 = (kc >> 3) + quad;          // source chunk within K-step
            int swz = (k8 ^ (l16 & 7)) << 4;    // swizzled byte offset of that chunk
            bf16x8 a[4], b[4];
#pragma unroll
            for (int mt = 0; mt < 4; mt++) {
                int row = wm * 64 + mt * 16 + l16;
                a[mt] = *(const bf16x8*)((const char*)As + row * 128 + swz);
            }
#pragma unroll
            for (int nt = 0; nt < 4; nt++) {
                int row = wn * 64 + nt * 16 + l16;
                b[nt] = *(const bf16x8*)((const char*)Bs + row * 128 + swz);
            }
#pragma unroll
            for (int mt = 0; mt < 4; mt++)
#pragma unroll
                for (int nt = 0; nt < 4; nt++)
                    acc[mt][nt] = __builtin_amdgcn_mfma_f32_16x16x32_bf16(a[mt], b[nt], acc[mt][nt], 0, 0, 0);
        }
        __syncthreads();
    }

#pragma unroll
    for (int mt = 0; mt < 4; mt++) {
#pragma unroll
        for (int nt = 0; nt < 4; nt++) {
            f32x4 a = acc[mt][nt];
            int colI = wn * 64 + nt * 16 + l16;
            float bv = bias[colI];
#pragma unroll
            for (int rr = 0; rr < 4; rr++) {
                int row = bm0 + wm * 64 + mt * 16 + quad * 4 + rr;
                if (row < M) {
                    float v = a[rr] + bv;
                    v = v > 0.f ? v : 0.f;
                    out[(long)row * ldo + ocol + colI] = f2bf(v);
                    if (dof8) {
                        int p = __builtin_amdgcn_cvt_pk_fp8_f32(v, v, 0, false);
                        x1f8[(long)row * 256 + colI] = (unsigned char)(p & 0xff);
                    }
                }
            }
        }
    }
}

// ---------------- head GEMM: 128 rows/block, 512 thr (8 waves, 4x2), N=64 ----------------
__global__ __launch_bounds__(512) void gemm_head_kernel(
    const unsigned short* __restrict__ Ax, int lda_x,
    const unsigned short* __restrict__ Bt, int K,
    const float* __restrict__ bias,
    void* __restrict__ out, int ldo,
    int M, int realN, const int* __restrict__ flagF) {
    __shared__ __align__(16) unsigned short As[128][64];   // 16 KB
    __shared__ __align__(16) unsigned short Bs[64][64];    // 8 KB
    int tid = threadIdx.x;
    int bm0 = blockIdx.x * 128;
    int wave = tid >> 6, lane = tid & 63;
    int wm = wave >> 1, wn = wave & 1;   // 4 x 2 waves
    int quad = lane >> 4, l16 = lane & 15;
    int lr = lane >> 3;
    int sc = (lane & 7) ^ lr;

    f32x4 acc[2][2];
#pragma unroll
    for (int mt = 0; mt < 2; mt++)
#pragma unroll
        for (int nt = 0; nt < 2; nt++) acc[mt][nt] = (f32x4){0.f, 0.f, 0.f, 0.f};

    for (int k0 = 0; k0 < K; k0 += 64) {
        // A tile: 16 chunks (128 rows x 128B); 8 waves x 2
#pragma unroll
        for (int i = 0; i < 2; i++) {
            int t = wave * 2 + i;
            int r = t * 8 + lr;
            int gr = bm0 + r; if (gr >= M) gr = M - 1;
            cp16(Ax + (long)gr * lda_x + k0 + sc * 8, (char*)As + t * 1024);
        }
        // B tile: 8 chunks (64 rows x 128B); 8 waves x 1
        {
            int t = wave;
            int r = t * 8 + lr;
            cp16(Bt + (long)r * K + k0 + sc * 8, (char*)Bs + t * 1024);
        }
        __syncthreads();
#pragma unroll
        for (int kc = 0; kc < 64; kc += 32) {
            int k8 = (kc >> 3) + quad;
            int swz = (k8 ^ (l16 & 7)) << 4;
            bf16x8 a0 = *(const bf16x8*)((const char*)As + (wm * 32 + l16) * 128 + swz);
            bf16x8 a1 = *(const bf16x8*)((const char*)As + (wm * 32 + 16 + l16) * 128 + swz);
#pragma unroll
            for (int nt = 0; nt < 2; nt++) {
                bf16x8 b = *(const bf16x8*)((const char*)Bs + (wn * 32 + nt * 16 + l16) * 128 + swz);
                acc[0][nt] = __builtin_amdgcn_mfma_f32_16x16x32_bf16(a0, b, acc[0][nt], 0, 0, 0);
                acc[1][nt] = __builtin_amdgcn_mfma_f32_16x16x32_bf16(a1, b, acc[1][nt], 0, 0, 0);
            }
        }
        __syncthreads();
    }

    int out_f32 = *flagF;
#pragma unroll
    for (int mt = 0; mt < 2; mt++) {
#pragma unroll
        for (int nt = 0; nt < 2; nt++) {
            f32x4 a = acc[mt][nt];
            int colI = wn * 32 + nt * 16 + l16;
            float bv = bias[colI];
#pragma unroll
            for (int rr = 0; rr < 4; rr++) {
                int row = bm0 + wm * 32 + mt * 16 + quad * 4 + rr;
                if (row < M && colI < realN) {
                    float v = a[rr] + bv;
                    long idx = (long)row * ldo + colI;
                    if (out_f32) ((float*)out)[idx] = v;
                    else ((unsigned short*)out)[idx] = f2bf(v);
                }
            }
        }
    }
}

extern "C" void kernel_launch(void* const* d_in, const int* in_sizes, int n_in,
                              void* d_out, int out_size, void* d_ws, size_t ws_size,
                              hipStream_t stream) {
    const void* x0  = d_in[0];
    const int*  ei  = (const int*)d_in[1];
    const void* ew  = d_in[2];
    const void* w1r = d_in[3];
    const void* b1h = d_in[4];
    const void* w1x = d_in[5];
    const void* w2r = d_in[6];
    const void* b2h = d_in[7];
    const void* w2x = d_in[8];
    const void* lw  = d_in[9];
    const void* lbh = d_in[10];

    // ---- workspace layout ----
    char* ws = (char*)d_ws;
    unsigned short* X12     = (unsigned short*)(ws);             // 51,200,000  [N x 512]
    unsigned int*   cw      = (unsigned int*)(ws + 51200000);    //  3,200,000
    int*            row_ptr = (int*)(ws + 54400000);             //    200,064
    unsigned short* Bt1     = (unsigned short*)(ws + 54800128);  //    131,072
    unsigned short* Bt2     = (unsigned short*)(ws + 54931200);  //    262,144
    unsigned short* Bt3     = (unsigned short*)(ws + 55193344);  //     65,536
    float*          b1      = (float*)(ws + 55258880);           //      1,024
    float*          b2      = (float*)(ws + 55259904);           //      1,024
    float*          b3      = (float*)(ws + 55260928);           //        256
    int*            flags   = (int*)(ws + 55261184);             //         64
    unsigned short* x0bf    = (unsigned short*)(ws + 55262272);  // 12,800,000 (fp32-input conv)
    unsigned char*  x1f8sep = (unsigned char*)(ws + 68062272);   // 12,800,000 (fp8 x1, tier-2)
    const size_t NEED_NOCONV = 55262272;
    const size_t NEED_FULL   = 68062272;  // + x0bf
    const size_t NEED_F8SEP  = 80862272;  // + separate x1f8

    // ---- radix-CSR scratch: lives inside X12, which is dead until agg1 ----
    uint2*        rec   = (uint2*)(ws);                          // 6,400,000 (<= E*8)
    unsigned int* bc    = (unsigned int*)(ws + 6400000);         // HB*NBKT*4 = 613,088
    unsigned int* pbse  = (unsigned int*)(ws + 7013120);         // 613,088
    unsigned int* btot  = (unsigned int*)(ws + 7626240);         // 1,024

    if (ws_size < NEED_NOCONV) {
        long n = (long)N_NODES * OUTC;
        zout_kernel<<<(int)((n + 255) / 256), 256, 0, stream>>>((unsigned short*)d_out, n);
        return;
    }
    int use_conv = (ws_size >= NEED_FULL) ? 1 : 0;
    // f8mode: 2 = separate buffer (always usable); 1 = alias x0bf (usable iff input bf16); 0 = off
    int f8mode = (ws_size >= NEED_F8SEP) ? 2 : (use_conv ? 1 : 0);
    unsigned char* x1f8 = (f8mode == 2) ? x1f8sep : (unsigned char*)x0bf;

    int* flagF = flags + 0;

    init_kernel<<<2, 256, 0, stream>>>((const unsigned int*)x0, flags, ei);

    int cb = use_conv ? ((N_NODES * IN_CH) / (256 * 8)) : 0;  // 3125 vectorized conv blocks
    {
        int ptotal = 256 * 256 + 256 * 512 + 64 * 512 + 256 + 256 + 64;
        int pblocks = (ptotal + 255) / 256;  // 899
        prep_all_kernel<<<cb + pblocks + HB, 256, 0, stream>>>(
            x0, cb, w1r, w1x, w2r, w2x, lw, b1h, b2h, lbh, flags, x0bf,
            Bt1, Bt2, Bt3, b1, b2, b3, ei, bc, pblocks);
    }

    // CSR build: two-level counting sort (LDS atomics only; no device-scope atomics)
    s1_kernel<<<NBKT, 1024, 0, stream>>>(bc, pbse, btot);
    f1_kernel<<<HB, 256, 0, stream>>>(ei, ew, flags, pbse, btot, rec);
    f2_kernel<<<NBKT, 512, 0, stream>>>(rec, btot, row_ptr, cw);

    int mblocks  = (N_NODES + 127) / 128;  // 391
    int hblocks  = (N_NODES + 127) / 128;  // 391 (head widened to 128 rows)
    int ablocks  = (N_NODES + 15) / 16;    // 3125

    const unsigned short* x0raw = (const unsigned short*)x0;

    // layer 1 (gemm epilogue also emits fp8 x1 when enabled)
    agg1_kernel<<<ablocks, 256, 0, stream>>>(x0raw, x0bf, use_conv, flags, row_ptr, cw, X12);
    gemm_big_kernel<<<mblocks, 512, 0, stream>>>(X12 + 256, 512, 128,
                                                 x0raw, x0bf, use_conv, IN_CH,
                                                 Bt1, 256, b1, flags,
                                                 X12, 512, 0, N_NODES, x1f8, f8mode);
    // layer-2 agg (fp8 gather when available)
    agg2_kernel<<<ablocks, 256, 0, stream>>>(row_ptr, cw, X12, x1f8, flags, f8mode);
    gemm_big_kernel<<<mblocks, 512, 0, stream>>>(X12 + 256, 512, 256,
                                                 X12, X12, 0, 512,
                                                 Bt2, 512, b2, flags,
                                                 X12, 512, 256, N_NODES,
                                                 (unsigned char*)nullptr, 0);
    // head
    gemm_head_kernel<<<hblocks, 512, 0, stream>>>(X12, 512, Bt3, 512, b3,
                                                  d_out, OUTC, N_NODES, OUTC, flagF);
}

// Round 12
// 262.705 us; speedup vs baseline: 1.0633x; 1.0065x over previous
//
#include <hip/hip_runtime.h>
#include <hip/hip_bf16.h>

#define N_NODES 50000
#define N_EDGES 800000
#define IN_CH   128
#define HID     256
#define OUTC    51

typedef __attribute__((ext_vector_type(8))) short  bf16x8;
typedef __attribute__((ext_vector_type(4))) float  f32x4;
typedef __attribute__((ext_vector_type(2))) float  f32x2;
typedef __attribute__((ext_vector_type(4))) unsigned int u32x4;

__device__ __forceinline__ float bf2f(unsigned short u) {
    union { unsigned int i; float f; } v; v.i = ((unsigned int)u) << 16; return v.f;
}
__device__ __forceinline__ unsigned short f2bf(float f) {
    union { float f; unsigned int i; } v; v.f = f;
    unsigned int u = v.i;
    unsigned int r = (u + 0x7fffu + ((u >> 16) & 1u)) >> 16;  // RNE
    return (unsigned short)r;
}
__device__ __forceinline__ unsigned short ldbf(const void* p, long i, int isf) {
    return isf ? f2bf(((const float*)p)[i]) : ((const unsigned short*)p)[i];
}
__device__ __forceinline__ float ldf(const void* p, long i, int isf) {
    return isf ? ((const float*)p)[i] : bf2f(((const unsigned short*)p)[i]);
}
__device__ __forceinline__ void load_edge_nt(const int* __restrict__ ei, int e, int is64,
                                             int* src, int* dst) {
    if (is64) { *src = __builtin_nontemporal_load(ei + 2 * e);
                *dst = __builtin_nontemporal_load(ei + 2 * (N_EDGES + e)); }
    else      { *src = __builtin_nontemporal_load(ei + e);
                *dst = __builtin_nontemporal_load(ei + N_EDGES + e); }
}

// async global->LDS 16B: wave-uniform LDS base, per-lane global src, HW dest = base + lane*16
typedef const __attribute__((address_space(1))) unsigned int* gas_u32;
typedef __attribute__((address_space(3))) unsigned int* las_u32;
__device__ __forceinline__ void cp16(const void* g, void* l) {
    __builtin_amdgcn_global_load_lds((gas_u32)g, (las_u32)l, 16, 0, 0);
}

// ---- radix-CSR constants ----
#define EBLK 1024                                // edges per histogram/fill block
#define HB   ((N_EDGES + EBLK - 1) / EBLK)       // 782 blocks
#define NBKT ((N_NODES + 255) / 256)             // 196 buckets of 256 nodes
#define F2STG 8192                               // f2 LDS staging entries (32KB; bucket mean 4082, +64 sd)

// ---------------- init: dtype probe + int64 detect (device probe is MANDATORY:
// in_sizes may be element counts, and fp32 vs bf16 have identical counts) ----------------
__global__ __launch_bounds__(256) void init_kernel(const unsigned int* __restrict__ x0w,
                                                   int* __restrict__ flags,
                                                   const int* __restrict__ ei) {
    int tid = threadIdx.x;
    if (blockIdx.x == 0) {
        if (tid < 64) {
            unsigned int w = x0w[tid];
            unsigned int ex = (w >> 7) & 0xFFu;
            unsigned long long bm = __ballot(ex >= 0x60u && ex <= 0x90u);
            if (tid == 0) flags[0] = (__popcll(bm) >= 48) ? 0 : 1;
        }
        return;
    }
    __shared__ int any;
    if (tid == 0) any = 0;
    __syncthreads();
    int acc = 0;
    for (int s = 0; s < 8; s++) {
        int i = (tid * 8 + s) * (N_EDGES / 2048);
        acc |= ei[2 * i + 1];
    }
    if (acc != 0) any = 1;
    __syncthreads();
    if (tid == 0) flags[1] = any;
}

// ---------------- prep_all: x0 convert (fp32 only, 8 elem/thr) + weight prep + edge histogram ----------------
__global__ void prep_all_kernel(const void* __restrict__ x0, int cb,
                                const void* __restrict__ w1r, const void* __restrict__ w1x,
                                const void* __restrict__ w2r, const void* __restrict__ w2x,
                                const void* __restrict__ lw,
                                const void* __restrict__ b1h, const void* __restrict__ b2h,
                                const void* __restrict__ lbh, const int* __restrict__ flags,
                                unsigned short* __restrict__ x0bf,
                                unsigned short* __restrict__ Bt1, unsigned short* __restrict__ Bt2,
                                unsigned short* __restrict__ Bt3,
                                float* __restrict__ b1, float* __restrict__ b2, float* __restrict__ b3,
                                const int* __restrict__ ei, unsigned int* __restrict__ bc,
                                int pblocks) {
    __shared__ unsigned int cnt[NBKT];
    int isf = flags[0];
    if ((int)blockIdx.x < cb) {
        if (!isf) return;  // bf16 input: skip copy
        long t0 = ((long)blockIdx.x * 256 + threadIdx.x) * 8;   // cb*256*8 == N*IN_CH exactly
        const float* xf = (const float*)x0;
        f32x4 v0 = *(const f32x4*)(xf + t0);
        f32x4 v1 = *(const f32x4*)(xf + t0 + 4);
        u32x4 pk;
        pk[0] = (unsigned int)f2bf(v0[0]) | ((unsigned int)f2bf(v0[1]) << 16);
        pk[1] = (unsigned int)f2bf(v0[2]) | ((unsigned int)f2bf(v0[3]) << 16);
        pk[2] = (unsigned int)f2bf(v1[0]) | ((unsigned int)f2bf(v1[1]) << 16);
        pk[3] = (unsigned int)f2bf(v1[2]) | ((unsigned int)f2bf(v1[3]) << 16);
        *(u32x4*)(x0bf + t0) = pk;
        return;
    }
    int rb = blockIdx.x - cb;
    if (rb >= pblocks) {
        // ---- histogram block ----
        int b = rb - pblocks;
        int tid = threadIdx.x;
        if (tid < NBKT) cnt[tid] = 0;
        __syncthreads();
        int is64 = (flags[1] == 0);
        int e0 = b * EBLK;
#pragma unroll
        for (int u = 0; u < 4; u++) {
            int e = e0 + u * 256 + tid;
            if (e < N_EDGES) {
                int src, dst; load_edge_nt(ei, e, is64, &src, &dst);
                if ((unsigned)src < N_NODES && (unsigned)dst < N_NODES)
                    atomicAdd(&cnt[dst >> 8], 1u);
            }
        }
        __syncthreads();
        if (tid < NBKT) bc[tid * HB + b] = cnt[tid];  // [bucket][block]
        return;
    }
    int t = rb * 256 + threadIdx.x;
    if (t < 256 * 256) {
        int n = t >> 8, k = t & 255;
        Bt1[n * 256 + k] = (k < 128) ? ldbf(w1r, k * 256 + n, isf) : ldbf(w1x, (k - 128) * 256 + n, isf);
        return;
    }
    t -= 256 * 256;
    if (t < 256 * 512) {
        int n = t >> 9, k = t & 511;
        Bt2[n * 512 + k] = (k < 256) ? ldbf(w2r, k * 256 + n, isf) : ldbf(w2x, (k - 256) * 256 + n, isf);
        return;
    }
    t -= 256 * 512;
    if (t < 64 * 512) {
        int n = t >> 9, k = t & 511;
        Bt3[n * 512 + k] = (n < OUTC) ? ldbf(lw, k * OUTC + n, isf) : (unsigned short)0;
        return;
    }
    t -= 64 * 512;
    if (t < 256) { b1[t] = ldf(b1h, t, isf); return; }
    t -= 256;
    if (t < 256) { b2[t] = ldf(b2h, t, isf); return; }
    t -= 256;
    if (t < 64)  { b3[t] = (t < OUTC) ? ldf(lbh, t, isf) : 0.0f; return; }
}

// ---------------- radix CSR scan 1: per-bucket prefix over blocks ----------------
__global__ __launch_bounds__(1024) void s1_kernel(const unsigned int* __restrict__ bc,
                                                  unsigned int* __restrict__ pbase,
                                                  unsigned int* __restrict__ total) {
    __shared__ unsigned int sd[1024];
    int b = blockIdx.x, tid = threadIdx.x;
    unsigned int v = (tid < HB) ? bc[b * HB + tid] : 0u;
    sd[tid] = v;
    __syncthreads();
    for (int off = 1; off < 1024; off <<= 1) {
        unsigned int t = (tid >= off) ? sd[tid - off] : 0u;
        __syncthreads();
        sd[tid] += t;
        __syncthreads();
    }
    if (tid < HB) pbase[tid * NBKT + b] = sd[tid] - v;  // [block][bucket], exclusive
    if (tid == 1023) total[b] = sd[1023];
}

// ---------------- radix CSR fill 1: scatter (w|src,dst) records into bucket regions ----------------
__global__ __launch_bounds__(256) void f1_kernel(const int* __restrict__ ei, const void* __restrict__ ew,
                                                 const int* __restrict__ flags,
                                                 const unsigned int* __restrict__ pbase,
                                                 const unsigned int* __restrict__ btot,
                                                 uint2* __restrict__ rec) {
    __shared__ unsigned int cur[NBKT];
    __shared__ unsigned int sb[256];
    int tid = threadIdx.x;
    unsigned int v = (tid < NBKT) ? btot[tid] : 0u;
    sb[tid] = v;
    __syncthreads();
    for (int off = 1; off < 256; off <<= 1) {
        unsigned int t = (tid >= off) ? sb[tid - off] : 0u;
        __syncthreads();
        sb[tid] += t;
        __syncthreads();
    }
    if (tid < NBKT) cur[tid] = (sb[tid] - v) + pbase[blockIdx.x * NBKT + tid];
    __syncthreads();
    int is64 = (flags[1] == 0);
    int isf = flags[0];
    int e0 = blockIdx.x * EBLK;
#pragma unroll
    for (int u = 0; u < 4; u++) {
        int e = e0 + u * 256 + tid;
        if (e < N_EDGES) {
            int src, dst; load_edge_nt(ei, e, is64, &src, &dst);
            if ((unsigned)src < N_NODES && (unsigned)dst < N_NODES) {
                unsigned int w = ldbf(ew, e, isf);
                unsigned int pos = atomicAdd(&cur[dst >> 8], 1u);
                uint2 r; r.x = (w << 16) | (unsigned)src; r.y = (unsigned)dst;
                rec[pos] = r;
            }
        }
    }
}

// ---------------- radix CSR fill 2: per-bucket sub-sort -> row_ptr + final cw ----------------
// v2: LDS-staged scatter (bucket cw slice ~16KB fits in LDS) -> contiguous global write-out,
// removing ~100MB of 4B scattered write-allocate traffic. Fallback to direct scatter if >F2STG.
__global__ __launch_bounds__(512) void f2_kernel(const uint2* __restrict__ rec,
                                                 const unsigned int* __restrict__ btot,
                                                 int* __restrict__ rp, unsigned int* __restrict__ cw) {
    __shared__ unsigned int sb[256], c2[256], sc[256], cur2[256];
    __shared__ unsigned int stg[F2STG];
    int tid = threadIdx.x, b = blockIdx.x;
    unsigned int vb = 0;
    if (tid < 256) { vb = (tid < NBKT) ? btot[tid] : 0u; sb[tid] = vb; }
    __syncthreads();
    for (int off = 1; off < 256; off <<= 1) {
        unsigned int t = (tid < 256 && tid >= off) ? sb[tid - off] : 0u;
        __syncthreads();
        if (tid < 256) sb[tid] += t;
        __syncthreads();
    }
    unsigned int s0 = (b > 0) ? sb[b - 1] : 0u;
    unsigned int e0 = sb[b];
    if (b == 0 && tid == 0) rp[N_NODES] = (int)sb[NBKT - 1];
    unsigned int cnt = e0 - s0;
    int fits = (cnt <= F2STG);
    if (tid < 256) c2[tid] = 0;
    __syncthreads();
    for (unsigned int pos = s0 + tid; pos < e0; pos += 512)
        atomicAdd(&c2[rec[pos].y & 255u], 1u);
    __syncthreads();
    unsigned int v = 0;
    if (tid < 256) { v = c2[tid]; sc[tid] = v; }
    __syncthreads();
    for (int off = 1; off < 256; off <<= 1) {
        unsigned int t = (tid < 256 && tid >= off) ? sc[tid - off] : 0u;
        __syncthreads();
        if (tid < 256) sc[tid] += t;
        __syncthreads();
    }
    if (tid < 256) {
        unsigned int lstart = sc[tid] - v;           // bucket-local start
        int node = b * 256 + tid;
        if (node < N_NODES) rp[node] = (int)(s0 + lstart);
        cur2[tid] = fits ? lstart : (s0 + lstart);
    }
    __syncthreads();
    if (fits) {
        for (unsigned int pos = s0 + tid; pos < e0; pos += 512) {
            uint2 r = rec[pos];
            unsigned int p = atomicAdd(&cur2[r.y & 255u], 1u);
            stg[p] = r.x;
        }
        __syncthreads();
        for (unsigned int i = tid; i < cnt; i += 512)
            cw[s0 + i] = stg[i];
    } else {
        for (unsigned int pos = s0 + tid; pos < e0; pos += 512) {
            uint2 r = rec[pos];
            unsigned int p = atomicAdd(&cur2[r.y & 255u], 1u);
            cw[p] = r.x;
        }
    }
}

// ---------------- fallback: zero output ----------------
__global__ __launch_bounds__(256) void zout_kernel(unsigned short* __restrict__ out, long n) {
    long t = (long)blockIdx.x * 256 + threadIdx.x;
    if (t < n) out[t] = 0;
}

// ---------------- agg1: 16 lanes/node x 16B (u32x4), 4 nodes/wave, bf16, 8 gathers in flight ----------------
__global__ __launch_bounds__(256) void agg1_kernel(const unsigned short* __restrict__ x0raw,
                                                   const unsigned short* __restrict__ x0conv,
                                                   int use_conv, const int* __restrict__ flags,
                                                   const int* __restrict__ rp, const unsigned int* __restrict__ cw,
                                                   unsigned short* __restrict__ X12) {
    const unsigned short* x0b = (use_conv && flags[0]) ? x0conv : x0raw;
    int r = blockIdx.x * 16 + (threadIdx.x >> 4);
    if (r >= N_NODES) return;
    int l = threadIdx.x & 15;
    int grpbase = threadIdx.x & 48;   // 16-lane group base within wave
    int js = rp[r], je = rp[r + 1];
    if (js < 0) js = 0;
    if (je > N_EDGES) je = N_EDGES;
    float a0 = 0.f, a1 = 0.f, a2 = 0.f, a3 = 0.f;
    float a4 = 0.f, a5 = 0.f, a6 = 0.f, a7 = 0.f;
    for (int base = js; base < je; base += 16) {
        int n = je - base; if (n > 16) n = 16;
        int idx = base + l; if (idx >= je) idx = je - 1;
        unsigned int rec = __builtin_nontemporal_load(cw + idx);
        for (int j = 0; j < n; j += 8) {
            int m = n - j; if (m > 8) m = 8;
            unsigned int vv[8]; u32x4 q[8];
#pragma unroll
            for (int u = 0; u < 8; u++) vv[u] = __shfl(rec, grpbase + j + u);
#pragma unroll
            for (int u = 0; u < 8; u++) if (u < m)
                q[u] = *(const u32x4*)(x0b + (long)(vv[u] & 0xFFFFu) * 128 + l * 8);
#pragma unroll
            for (int u = 0; u < 8; u++) if (u < m) {
                float w = bf2f((unsigned short)(vv[u] >> 16));
                a0 += w * bf2f((unsigned short)(q[u][0] & 0xffffu));
                a1 += w * bf2f((unsigned short)(q[u][0] >> 16));
                a2 += w * bf2f((unsigned short)(q[u][1] & 0xffffu));
                a3 += w * bf2f((unsigned short)(q[u][1] >> 16));
                a4 += w * bf2f((unsigned short)(q[u][2] & 0xffffu));
                a5 += w * bf2f((unsigned short)(q[u][2] >> 16));
                a6 += w * bf2f((unsigned short)(q[u][3] & 0xffffu));
                a7 += w * bf2f((unsigned short)(q[u][3] >> 16));
            }
        }
    }
    u32x4 pk;
    pk[0] = (unsigned int)f2bf(a0) | ((unsigned int)f2bf(a1) << 16);
    pk[1] = (unsigned int)f2bf(a2) | ((unsigned int)f2bf(a3) << 16);
    pk[2] = (unsigned int)f2bf(a4) | ((unsigned int)f2bf(a5) << 16);
    pk[3] = (unsigned int)f2bf(a6) | ((unsigned int)f2bf(a7) << 16);
    *(u32x4*)&X12[(long)r * 512 + 256 + l * 8] = pk;
}

// ---------------- agg2: 16 lanes/node x 16B, fp8 (8 deep) or bf16 (4 deep) (R3 best-known) ----------------
__global__ __launch_bounds__(256) void agg2_kernel(const int* __restrict__ rp, const unsigned int* __restrict__ cw,
                                                   unsigned short* __restrict__ X12,
                                                   const unsigned char* __restrict__ x1f8,
                                                   const int* __restrict__ flags, int f8mode) {
    int usef8 = (f8mode == 2) || (f8mode == 1 && flags[0] == 0);
    int r = blockIdx.x * 16 + (threadIdx.x >> 4);
    if (r >= N_NODES) return;
    int l = threadIdx.x & 15;
    int grpbase = threadIdx.x & 48;
    int js = rp[r], je = rp[r + 1];
    if (js < 0) js = 0;
    if (je > N_EDGES) je = N_EDGES;
    float a[16];
#pragma unroll
    for (int c = 0; c < 16; c++) a[c] = 0.f;
    if (usef8) {
        for (int base = js; base < je; base += 16) {
            int n = je - base; if (n > 16) n = 16;
            int idx = base + l; if (idx >= je) idx = je - 1;
            unsigned int rec = __builtin_nontemporal_load(cw + idx);
            for (int j = 0; j < n; j += 8) {
                int m = n - j; if (m > 8) m = 8;
                unsigned int vv[8]; u32x4 q[8];
#pragma unroll
                for (int u = 0; u < 8; u++) vv[u] = __shfl(rec, grpbase + j + u);
#pragma unroll
                for (int u = 0; u < 8; u++) if (u < m)
                    q[u] = *(const u32x4*)(x1f8 + (long)(vv[u] & 0xFFFFu) * 256 + l * 16);
#pragma unroll
                for (int u = 0; u < 8; u++) if (u < m) {
                    float w = bf2f((unsigned short)(vv[u] >> 16));
#pragma unroll
                    for (int c = 0; c < 4; c++) {
                        f32x2 plo = __builtin_amdgcn_cvt_pk_f32_fp8((int)q[u][c], false);
                        f32x2 phi = __builtin_amdgcn_cvt_pk_f32_fp8((int)q[u][c], true);
                        a[c * 4 + 0] += w * plo.x; a[c * 4 + 1] += w * plo.y;
                        a[c * 4 + 2] += w * phi.x; a[c * 4 + 3] += w * phi.y;
                    }
                }
            }
        }
    } else {
        for (int base = js; base < je; base += 16) {
            int n = je - base; if (n > 16) n = 16;
            int idx = base + l; if (idx >= je) idx = je - 1;
            unsigned int rec = __builtin_nontemporal_load(cw + idx);
            for (int j = 0; j < n; j += 4) {
                int m = n - j; if (m > 4) m = 4;
                unsigned int vv[4]; u32x4 q0[4], q1[4];
#pragma unroll
                for (int u = 0; u < 4; u++) vv[u] = __shfl(rec, grpbase + j + u);
#pragma unroll
                for (int u = 0; u < 4; u++) if (u < m) {
                    const unsigned short* sp = X12 + (long)(vv[u] & 0xFFFFu) * 512 + l * 16;
                    q0[u] = *(const u32x4*)sp;
                    q1[u] = *(const u32x4*)(sp + 8);
                }
#pragma unroll
                for (int u = 0; u < 4; u++) if (u < m) {
                    float w = bf2f((unsigned short)(vv[u] >> 16));
#pragma unroll
                    for (int c = 0; c < 4; c++) {
                        a[c * 2 + 0] += w * bf2f((unsigned short)(q0[u][c] & 0xffffu));
                        a[c * 2 + 1] += w * bf2f((unsigned short)(q0[u][c] >> 16));
                        a[8 + c * 2 + 0] += w * bf2f((unsigned short)(q1[u][c] & 0xffffu));
                        a[8 + c * 2 + 1] += w * bf2f((unsigned short)(q1[u][c] >> 16));
                    }
                }
            }
        }
    }
    u32x4 p0, p1;
#pragma unroll
    for (int c = 0; c < 4; c++) {
        p0[c] = (unsigned int)f2bf(a[c * 2]) | ((unsigned int)f2bf(a[c * 2 + 1]) << 16);
        p1[c] = (unsigned int)f2bf(a[8 + c * 2]) | ((unsigned int)f2bf(a[8 + c * 2 + 1]) << 16);
    }
    unsigned short* op = &X12[(long)r * 512 + 256 + l * 16];
    *(u32x4*)op = p0;
    *(u32x4*)(op + 8) = p1;
}

// ---------------- big MFMA GEMM: 128x256 tile, 512 thr (8 waves, 2x4) ----------------
__global__ __launch_bounds__(512) void gemm_big_kernel(
    const unsigned short* __restrict__ Aagg, int lda_agg, int Kagg,
    const unsigned short* __restrict__ AxRaw, const unsigned short* __restrict__ AxConv,
    int use_conv, int lda_x,
    const unsigned short* __restrict__ Bt, int K,
    const float* __restrict__ bias, const int* __restrict__ flags,
    unsigned short* __restrict__ out, int ldo, int ocol, int M,
    unsigned char* __restrict__ x1f8, int f8mode) {
    __shared__ __align__(16) unsigned short As[128][64];   // 16 KB, 128 B/row
    __shared__ __align__(16) unsigned short Bs[256][64];   // 32 KB
    const unsigned short* Ax = (use_conv && flags[0]) ? AxConv : AxRaw;
    int dof8 = (f8mode == 2) || (f8mode == 1 && flags[0] == 0);
    int tid = threadIdx.x;
    int bm0 = blockIdx.x * 128;
    int wave = tid >> 6, lane = tid & 63;
    int wm = wave >> 2, wn = wave & 3;
    int quad = lane >> 4, l16 = lane & 15;
    int lr = lane >> 3;            // row within 8-row chunk (0..7)
    int sc = (lane & 7) ^ lr;      // source chunk for this lane's dest slot

    f32x4 acc[4][4];
#pragma unroll
    for (int mt = 0; mt < 4; mt++)
#pragma unroll
        for (int nt = 0; nt < 4; nt++) acc[mt][nt] = (f32x4){0.f, 0.f, 0.f, 0.f};

    for (int k0 = 0; k0 < K; k0 += 64) {
        const unsigned short* srcp;
        int stride, koff;
        if (k0 < Kagg) { srcp = Aagg; stride = lda_agg; koff = k0; }
        else           { srcp = Ax;   stride = lda_x;   koff = k0 - Kagg; }
        // A tile: 16 chunks of 1 KB (8 rows x 128 B each); wave covers 2
#pragma unroll
        for (int i = 0; i < 2; i++) {
            int t = wave * 2 + i;
            int r = t * 8 + lr;
            int gr = bm0 + r; if (gr >= M) gr = M - 1;
            cp16(srcp + (long)gr * stride + koff + sc * 8, (char*)As + t * 1024);
        }
        // B tile: 32 chunks; wave covers 4
#pragma unroll
        for (int i = 0; i < 4; i++) {
            int t = wave * 4 + i;
            int r = t * 8 + lr;
            cp16(Bt + (long)r * K + k0 + sc * 8, (char*)Bs + t * 1024);
        }
        __syncthreads();
#pragma unroll
        for (int kc = 0; kc < 64; kc += 32) {
            int k8 = (kc >> 3) + quad;          // source chunk within K-step
            int swz = (k8 ^ (l16 & 7)) << 4;    // swizzled byte offset of that chunk
            bf16x8 a[4], b[4];
#pragma unroll
            for (int mt = 0; mt < 4; mt++) {
                int row = wm * 64 + mt * 16 + l16;
                a[mt] = *(const bf16x8*)((const char*)As + row * 128 + swz);
            }
#pragma unroll
            for (int nt = 0; nt < 4; nt++) {
                int row = wn * 64 + nt * 16 + l16;
                b[nt] = *(const bf16x8*)((const char*)Bs + row * 128 + swz);
            }
#pragma unroll
            for (int mt = 0; mt < 4; mt++)
#pragma unroll
                for (int nt = 0; nt < 4; nt++)
                    acc[mt][nt] = __builtin_amdgcn_mfma_f32_16x16x32_bf16(a[mt], b[nt], acc[mt][nt], 0, 0, 0);
        }
        __syncthreads();
    }

#pragma unroll
    for (int mt = 0; mt < 4; mt++) {
#pragma unroll
        for (int nt = 0; nt < 4; nt++) {
            f32x4 a = acc[mt][nt];
            int colI = wn * 64 + nt * 16 + l16;
            float bv = bias[colI];
#pragma unroll
            for (int rr = 0; rr < 4; rr++) {
                int row = bm0 + wm * 64 + mt * 16 + quad * 4 + rr;
                if (row < M) {
                    float v = a[rr] + bv;
                    v = v > 0.f ? v : 0.f;
                    out[(long)row * ldo + ocol + colI] = f2bf(v);
                    if (dof8) {
                        int p = __builtin_amdgcn_cvt_pk_fp8_f32(v, v, 0, false);
                        x1f8[(long)row * 256 + colI] = (unsigned char)(p & 0xff);
                    }
                }
            }
        }
    }
}

// ---------------- head GEMM: 128 rows/block, 512 thr (8 waves, 4x2), N=64 ----------------
__global__ __launch_bounds__(512) void gemm_head_kernel(
    const unsigned short* __restrict__ Ax, int lda_x,
    const unsigned short* __restrict__ Bt, int K,
    const float* __restrict__ bias,
    void* __restrict__ out, int ldo,
    int M, int realN, const int* __restrict__ flagF) {
    __shared__ __align__(16) unsigned short As[128][64];   // 16 KB
    __shared__ __align__(16) unsigned short Bs[64][64];    // 8 KB
    int tid = threadIdx.x;
    int bm0 = blockIdx.x * 128;
    int wave = tid >> 6, lane = tid & 63;
    int wm = wave >> 1, wn = wave & 1;   // 4 x 2 waves
    int quad = lane >> 4, l16 = lane & 15;
    int lr = lane >> 3;
    int sc = (lane & 7) ^ lr;

    f32x4 acc[2][2];
#pragma unroll
    for (int mt = 0; mt < 2; mt++)
#pragma unroll
        for (int nt = 0; nt < 2; nt++) acc[mt][nt] = (f32x4){0.f, 0.f, 0.f, 0.f};

    for (int k0 = 0; k0 < K; k0 += 64) {
        // A tile: 16 chunks (128 rows x 128B); 8 waves x 2
#pragma unroll
        for (int i = 0; i < 2; i++) {
            int t = wave * 2 + i;
            int r = t * 8 + lr;
            int gr = bm0 + r; if (gr >= M) gr = M - 1;
            cp16(Ax + (long)gr * lda_x + k0 + sc * 8, (char*)As + t * 1024);
        }
        // B tile: 8 chunks (64 rows x 128B); 8 waves x 1
        {
            int t = wave;
            int r = t * 8 + lr;
            cp16(Bt + (long)r * K + k0 + sc * 8, (char*)Bs + t * 1024);
        }
        __syncthreads();
#pragma unroll
        for (int kc = 0; kc < 64; kc += 32) {
            int k8 = (kc >> 3) + quad;
            int swz = (k8 ^ (l16 & 7)) << 4;
            bf16x8 a0 = *(const bf16x8*)((const char*)As + (wm * 32 + l16) * 128 + swz);
            bf16x8 a1 = *(const bf16x8*)((const char*)As + (wm * 32 + 16 + l16) * 128 + swz);
#pragma unroll
            for (int nt = 0; nt < 2; nt++) {
                bf16x8 b = *(const bf16x8*)((const char*)Bs + (wn * 32 + nt * 16 + l16) * 128 + swz);
                acc[0][nt] = __builtin_amdgcn_mfma_f32_16x16x32_bf16(a0, b, acc[0][nt], 0, 0, 0);
                acc[1][nt] = __builtin_amdgcn_mfma_f32_16x16x32_bf16(a1, b, acc[1][nt], 0, 0, 0);
            }
        }
        __syncthreads();
    }

    int out_f32 = *flagF;
#pragma unroll
    for (int mt = 0; mt < 2; mt++) {
#pragma unroll
        for (int nt = 0; nt < 2; nt++) {
            f32x4 a = acc[mt][nt];
            int colI = wn * 32 + nt * 16 + l16;
            float bv = bias[colI];
#pragma unroll
            for (int rr = 0; rr < 4; rr++) {
                int row = bm0 + wm * 32 + mt * 16 + quad * 4 + rr;
                if (row < M && colI < realN) {
                    float v = a[rr] + bv;
                    long idx = (long)row * ldo + colI;
                    if (out_f32) ((float*)out)[idx] = v;
                    else ((unsigned short*)out)[idx] = f2bf(v);
                }
            }
        }
    }
}

extern "C" void kernel_launch(void* const* d_in, const int* in_sizes, int n_in,
                              void* d_out, int out_size, void* d_ws, size_t ws_size,
                              hipStream_t stream) {
    const void* x0  = d_in[0];
    const int*  ei  = (const int*)d_in[1];
    const void* ew  = d_in[2];
    const void* w1r = d_in[3];
    const void* b1h = d_in[4];
    const void* w1x = d_in[5];
    const void* w2r = d_in[6];
    const void* b2h = d_in[7];
    const void* w2x = d_in[8];
    const void* lw  = d_in[9];
    const void* lbh = d_in[10];

    // ---- workspace layout ----
    char* ws = (char*)d_ws;
    unsigned short* X12     = (unsigned short*)(ws);             // 51,200,000  [N x 512]
    unsigned int*   cw      = (unsigned int*)(ws + 51200000);    //  3,200,000
    int*            row_ptr = (int*)(ws + 54400000);             //    200,064
    unsigned short* Bt1     = (unsigned short*)(ws + 54800128);  //    131,072
    unsigned short* Bt2     = (unsigned short*)(ws + 54931200);  //    262,144
    unsigned short* Bt3     = (unsigned short*)(ws + 55193344);  //     65,536
    float*          b1      = (float*)(ws + 55258880);           //      1,024
    float*          b2      = (float*)(ws + 55259904);           //      1,024
    float*          b3      = (float*)(ws + 55260928);           //        256
    int*            flags   = (int*)(ws + 55261184);             //         64
    unsigned short* x0bf    = (unsigned short*)(ws + 55262272);  // 12,800,000 (fp32-input conv)
    unsigned char*  x1f8sep = (unsigned char*)(ws + 68062272);   // 12,800,000 (fp8 x1, tier-2)
    const size_t NEED_NOCONV = 55262272;
    const size_t NEED_FULL   = 68062272;  // + x0bf
    const size_t NEED_F8SEP  = 80862272;  // + separate x1f8

    // ---- radix-CSR scratch: lives inside X12, which is dead until agg1 ----
    uint2*        rec   = (uint2*)(ws);                          // 6,400,000 (<= E*8)
    unsigned int* bc    = (unsigned int*)(ws + 6400000);         // HB*NBKT*4 = 613,088
    unsigned int* pbse  = (unsigned int*)(ws + 7013120);         // 613,088
    unsigned int* btot  = (unsigned int*)(ws + 7626240);         // 1,024

    if (ws_size < NEED_NOCONV) {
        long n = (long)N_NODES * OUTC;
        zout_kernel<<<(int)((n + 255) / 256), 256, 0, stream>>>((unsigned short*)d_out, n);
        return;
    }
    int use_conv = (ws_size >= NEED_FULL) ? 1 : 0;
    // f8mode: 2 = separate buffer (always usable); 1 = alias x0bf (usable iff input bf16); 0 = off
    int f8mode = (ws_size >= NEED_F8SEP) ? 2 : (use_conv ? 1 : 0);
    unsigned char* x1f8 = (f8mode == 2) ? x1f8sep : (unsigned char*)x0bf;

    int* flagF = flags + 0;

    init_kernel<<<2, 256, 0, stream>>>((const unsigned int*)x0, flags, ei);

    int cb = use_conv ? ((N_NODES * IN_CH) / (256 * 8)) : 0;  // 3125 vectorized conv blocks
    {
        int ptotal = 256 * 256 + 256 * 512 + 64 * 512 + 256 + 256 + 64;
        int pblocks = (ptotal + 255) / 256;  // 899
        prep_all_kernel<<<cb + pblocks + HB, 256, 0, stream>>>(
            x0, cb, w1r, w1x, w2r, w2x, lw, b1h, b2h, lbh, flags, x0bf,
            Bt1, Bt2, Bt3, b1, b2, b3, ei, bc, pblocks);
    }

    // CSR build: two-level counting sort (LDS atomics only; no device-scope atomics)
    s1_kernel<<<NBKT, 1024, 0, stream>>>(bc, pbse, btot);
    f1_kernel<<<HB, 256, 0, stream>>>(ei, ew, flags, pbse, btot, rec);
    f2_kernel<<<NBKT, 512, 0, stream>>>(rec, btot, row_ptr, cw);

    int mblocks  = (N_NODES + 127) / 128;  // 391
    int hblocks  = (N_NODES + 127) / 128;  // 391 (head: 128 rows/block)
    int ablocks  = (N_NODES + 15) / 16;    // 3125

    const unsigned short* x0raw = (const unsigned short*)x0;

    // layer 1 (gemm epilogue also emits fp8 x1 when enabled)
    agg1_kernel<<<ablocks, 256, 0, stream>>>(x0raw, x0bf, use_conv, flags, row_ptr, cw, X12);
    gemm_big_kernel<<<mblocks, 512, 0, stream>>>(X12 + 256, 512, 128,
                                                 x0raw, x0bf, use_conv, IN_CH,
                                                 Bt1, 256, b1, flags,
                                                 X12, 512, 0, N_NODES, x1f8, f8mode);
    // layer-2 agg (fp8 gather when available)
    agg2_kernel<<<ablocks, 256, 0, stream>>>(row_ptr, cw, X12, x1f8, flags, f8mode);
    gemm_big_kernel<<<mblocks, 512, 0, stream>>>(X12 + 256, 512, 256,
                                                 X12, X12, 0, 512,
                                                 Bt2, 512, b2, flags,
                                                 X12, 512, 256, N_NODES,
                                                 (unsigned char*)nullptr, 0);
    // head
    gemm_head_kernel<<<hblocks, 512, 0, stream>>>(X12, 512, Bt3, 512, b3,
                                                  d_out, OUTC, N_NODES, OUTC, flagF);
}